// Round 1
// baseline (1190.607 us; speedup 1.0000x reference)
//
#include <hip/hip_runtime.h>
#include <math.h>

namespace {
constexpr int Bb = 2;
constexpr int Ll = 2048;
constexpr int Dd = 1024;
constexpr int Hh = 16;
constexpr int NT = Bb * Ll;   // 4096 tokens
constexpr int D3 = 3 * Dd;    // 3072
constexpr int PH = Dd / 2;    // 512 phases per token
}

// C[n,m] = bias[m] + sum_k A[n,k] * W[m,k]   (A: NxK row-major, W: MxK row-major)
// 128x128 tile, 256 threads, 8x8 per thread, BK=16, transposed LDS (k-major rows).
__global__ __launch_bounds__(256) void gemm_nt_128(
    const float* __restrict__ A, const float* __restrict__ W,
    const float* __restrict__ bias, float* __restrict__ C,
    int K, int M)
{
  constexpr int BK = 16;
  __shared__ float As[BK][132];   // stride 132 floats = 528B (16B-aligned rows)
  __shared__ float Ws[BK][132];
  const int tid = threadIdx.x;
  const int m0 = blockIdx.x * 128;
  const int n0 = blockIdx.y * 128;
  const int ty = tid >> 4, tx = tid & 15;
  const int lrow = tid >> 2, lseg = tid & 3;

  float acc[8][8];
#pragma unroll
  for (int i = 0; i < 8; ++i)
#pragma unroll
    for (int j = 0; j < 8; ++j) acc[i][j] = 0.f;

  for (int k0 = 0; k0 < K; k0 += BK) {
#pragma unroll
    for (int r = 0; r < 2; ++r) {
      const int row = lrow + r * 64;
      const float4 av = *(const float4*)(A + (n0 + row) * K + k0 + lseg * 4);
      As[lseg*4+0][row] = av.x; As[lseg*4+1][row] = av.y;
      As[lseg*4+2][row] = av.z; As[lseg*4+3][row] = av.w;
      const float4 wv = *(const float4*)(W + (m0 + row) * K + k0 + lseg * 4);
      Ws[lseg*4+0][row] = wv.x; Ws[lseg*4+1][row] = wv.y;
      Ws[lseg*4+2][row] = wv.z; Ws[lseg*4+3][row] = wv.w;
    }
    __syncthreads();
#pragma unroll
    for (int kk = 0; kk < BK; ++kk) {
      const float4 a0 = *(const float4*)&As[kk][ty*8];
      const float4 a1 = *(const float4*)&As[kk][ty*8+4];
      const float4 b0 = *(const float4*)&Ws[kk][tx*8];
      const float4 b1 = *(const float4*)&Ws[kk][tx*8+4];
      const float a[8] = {a0.x,a0.y,a0.z,a0.w,a1.x,a1.y,a1.z,a1.w};
      const float b[8] = {b0.x,b0.y,b0.z,b0.w,b1.x,b1.y,b1.z,b1.w};
#pragma unroll
      for (int i = 0; i < 8; ++i)
#pragma unroll
        for (int j = 0; j < 8; ++j) acc[i][j] = fmaf(a[i], b[j], acc[i][j]);
    }
    __syncthreads();
  }
  float bv[8];
#pragma unroll
  for (int j = 0; j < 8; ++j) bv[j] = bias[m0 + tx*8 + j];
#pragma unroll
  for (int i = 0; i < 8; ++i) {
    float* crow = C + (n0 + ty*8 + i) * M + m0 + tx*8;
    *(float4*)(crow)     = make_float4(acc[i][0]+bv[0], acc[i][1]+bv[1],
                                       acc[i][2]+bv[2], acc[i][3]+bv[3]);
    *(float4*)(crow + 4) = make_float4(acc[i][4]+bv[4], acc[i][5]+bv[5],
                                       acc[i][6]+bv[6], acc[i][7]+bv[7]);
  }
}

// C[n,m] = sum_k A[n,k] * Bm[k,m]   (A: NxK row-major, Bm: KxM row-major)
// 64x64 tile, 256 threads, 4x4 per thread, BK=32.
__global__ __launch_bounds__(256) void gemm_nn_64(
    const float* __restrict__ A, const float* __restrict__ Bm,
    float* __restrict__ C, int K, int M)
{
  constexpr int BK = 32;
  __shared__ float As[BK][68];
  __shared__ float Bs[BK][68];
  const int tid = threadIdx.x;
  const int m0 = blockIdx.x * 64;
  const int n0 = blockIdx.y * 64;
  const int ty = tid >> 4, tx = tid & 15;

  float acc[4][4];
#pragma unroll
  for (int i = 0; i < 4; ++i)
#pragma unroll
    for (int j = 0; j < 4; ++j) acc[i][j] = 0.f;

  for (int k0 = 0; k0 < K; k0 += BK) {
#pragma unroll
    for (int r = 0; r < 2; ++r) {
      const int idx = r * 256 + tid;
      const int ar = idx >> 3, as = idx & 7;           // A: 64 rows x 8 float4
      const float4 av = *(const float4*)(A + (n0 + ar) * K + k0 + as * 4);
      As[as*4+0][ar] = av.x; As[as*4+1][ar] = av.y;
      As[as*4+2][ar] = av.z; As[as*4+3][ar] = av.w;
      const int br = idx >> 4, bs = idx & 15;          // B: 32 rows x 16 float4
      *(float4*)&Bs[br][bs*4] = *(const float4*)(Bm + (k0 + br) * M + m0 + bs * 4);
    }
    __syncthreads();
#pragma unroll
    for (int kk = 0; kk < BK; ++kk) {
      const float4 a4 = *(const float4*)&As[kk][ty*4];
      const float4 b4 = *(const float4*)&Bs[kk][tx*4];
      const float a[4] = {a4.x,a4.y,a4.z,a4.w};
      const float b[4] = {b4.x,b4.y,b4.z,b4.w};
#pragma unroll
      for (int i = 0; i < 4; ++i)
#pragma unroll
        for (int j = 0; j < 4; ++j) acc[i][j] = fmaf(a[i], b[j], acc[i][j]);
    }
    __syncthreads();
  }
#pragma unroll
  for (int i = 0; i < 4; ++i) {
    *(float4*)(C + (n0 + ty*4 + i) * M + m0 + tx*4) =
        make_float4(acc[i][0], acc[i][1], acc[i][2], acc[i][3]);
  }
}

// In-place rotary on q and k halves using phases; one thread per (token, head, i<32).
__global__ __launch_bounds__(256) void rot_kernel(
    const float* __restrict__ phases, float* __restrict__ qkv)
{
  const int gid = blockIdx.x * 256 + threadIdx.x;   // NT*H*32 = 2M
  const int i = gid & 31;
  const int h = (gid >> 5) & 15;
  const int n = gid >> 9;
  const float ph = phases[n * PH + h * 32 + i];
  float sn, cs;
  sincosf(ph, &sn, &cs);
  const int base = n * D3 + h * 64 + i;
  const float q1 = qkv[base], q2 = qkv[base + 32];
  qkv[base]      = q1 * cs - q2 * sn;
  qkv[base + 32] = q1 * sn + q2 * cs;
  const float k1 = qkv[base + Dd], k2 = qkv[base + Dd + 32];
  qkv[base + Dd]      = k1 * cs - k2 * sn;
  qkv[base + Dd + 32] = k1 * sn + k2 * cs;
}

// Flash attention: block = (q-tile of 64) x (b,h). 64x64 K/V tiles, online softmax.
// LDS: Qs (Q^T), KP (K^T, then reused for P row-major), Vs (row-major). 52.2 KB.
__global__ __launch_bounds__(256) void attn_kernel(
    const float* __restrict__ qkv, float* __restrict__ aout)
{
  __shared__ float Qs[64][68];
  __shared__ float KP[64][68];
  __shared__ float Vs[64][68];
  const int tid = threadIdx.x;
  const int q0 = blockIdx.x * 64;
  const int bh = blockIdx.y;
  const int b = bh >> 4, h = bh & 15;
  const int ty = tid >> 4, tx = tid & 15;
  const int srow = tid >> 4, sseg = tid & 15;

  // stage Q transposed, fold in scale 1/sqrt(64)=0.125
  const int qbase = (b * Ll + q0) * D3 + h * 64;
#pragma unroll
  for (int r = 0; r < 4; ++r) {
    const int row = srow + r * 16;
    const float4 v = *(const float4*)(qkv + qbase + row * D3 + sseg * 4);
    Qs[sseg*4+0][row] = v.x * 0.125f;
    Qs[sseg*4+1][row] = v.y * 0.125f;
    Qs[sseg*4+2][row] = v.z * 0.125f;
    Qs[sseg*4+3][row] = v.w * 0.125f;
  }

  float o[4][4];
#pragma unroll
  for (int i = 0; i < 4; ++i)
#pragma unroll
    for (int c = 0; c < 4; ++c) o[i][c] = 0.f;
  float mrow[4] = {-3e38f, -3e38f, -3e38f, -3e38f};
  float lsum[4] = {0.f, 0.f, 0.f, 0.f};

  for (int kt = 0; kt < Ll / 64; ++kt) {
    __syncthreads();  // prior PV done with KP(P) & Vs
    const int kbase = (b * Ll + kt * 64) * D3 + Dd + h * 64;
    const int vbase = kbase + Dd;
#pragma unroll
    for (int r = 0; r < 4; ++r) {
      const int row = srow + r * 16;
      const float4 kv = *(const float4*)(qkv + kbase + row * D3 + sseg * 4);
      KP[sseg*4+0][row] = kv.x; KP[sseg*4+1][row] = kv.y;
      KP[sseg*4+2][row] = kv.z; KP[sseg*4+3][row] = kv.w;
      const float4 vv = *(const float4*)(qkv + vbase + row * D3 + sseg * 4);
      *(float4*)&Vs[row][sseg*4] = vv;
    }
    __syncthreads();

    // S tile: rows i = ty*4+ii, cols j = tx*4+jj
    float s[4][4];
#pragma unroll
    for (int i = 0; i < 4; ++i)
#pragma unroll
      for (int j = 0; j < 4; ++j) s[i][j] = 0.f;
#pragma unroll
    for (int d = 0; d < 64; ++d) {
      const float4 qa = *(const float4*)&Qs[d][ty*4];
      const float4 kb = *(const float4*)&KP[d][tx*4];
      const float aq[4] = {qa.x,qa.y,qa.z,qa.w};
      const float bk[4] = {kb.x,kb.y,kb.z,kb.w};
#pragma unroll
      for (int i = 0; i < 4; ++i)
#pragma unroll
        for (int j = 0; j < 4; ++j) s[i][j] = fmaf(aq[i], bk[j], s[i][j]);
    }

    // online softmax per row (row group = 16 consecutive lanes, reduce via shfl_xor)
    float alpha[4];
#pragma unroll
    for (int i = 0; i < 4; ++i) {
      float v = fmaxf(fmaxf(s[i][0], s[i][1]), fmaxf(s[i][2], s[i][3]));
#pragma unroll
      for (int msk = 8; msk >= 1; msk >>= 1) v = fmaxf(v, __shfl_xor(v, msk));
      const float mnew = fmaxf(mrow[i], v);
      alpha[i] = __expf(mrow[i] - mnew);
      mrow[i] = mnew;
      float rs = 0.f;
#pragma unroll
      for (int j = 0; j < 4; ++j) {
        const float pv = __expf(s[i][j] - mnew);
        s[i][j] = pv; rs += pv;
      }
#pragma unroll
      for (int msk = 8; msk >= 1; msk >>= 1) rs += __shfl_xor(rs, msk);
      lsum[i] = lsum[i] * alpha[i] + rs;
#pragma unroll
      for (int c = 0; c < 4; ++c) o[i][c] *= alpha[i];
    }
    __syncthreads();  // everyone done reading KP as K
#pragma unroll
    for (int i = 0; i < 4; ++i)
#pragma unroll
      for (int j = 0; j < 4; ++j) KP[ty*4+i][tx*4+j] = s[i][j];
    __syncthreads();  // P visible

    // O += P * V : o[ii][cc], cc cols = tx*4..
#pragma unroll
    for (int jg = 0; jg < 16; ++jg) {
      float p[4][4], vv[4][4];
#pragma unroll
      for (int i = 0; i < 4; ++i) {
        const float4 t = *(const float4*)&KP[ty*4+i][jg*4];
        p[i][0]=t.x; p[i][1]=t.y; p[i][2]=t.z; p[i][3]=t.w;
      }
#pragma unroll
      for (int j = 0; j < 4; ++j) {
        const float4 t = *(const float4*)&Vs[jg*4+j][tx*4];
        vv[j][0]=t.x; vv[j][1]=t.y; vv[j][2]=t.z; vv[j][3]=t.w;
      }
#pragma unroll
      for (int i = 0; i < 4; ++i)
#pragma unroll
        for (int j = 0; j < 4; ++j)
#pragma unroll
          for (int c = 0; c < 4; ++c) o[i][c] = fmaf(p[i][j], vv[j][c], o[i][c]);
    }
  }

#pragma unroll
  for (int i = 0; i < 4; ++i) {
    const float inv = 1.f / lsum[i];
    *(float4*)(aout + (b * Ll + q0 + ty*4 + i) * Dd + h * 64 + tx*4) =
        make_float4(o[i][0]*inv, o[i][1]*inv, o[i][2]*inv, o[i][3]*inv);
  }
}

extern "C" void kernel_launch(void* const* d_in, const int* in_sizes, int n_in,
                              void* d_out, int out_size, void* d_ws, size_t ws_size,
                              hipStream_t stream) {
  const float* x     = (const float*)d_in[0];
  const float* p     = (const float*)d_in[1];
  const float* W_qkv = (const float*)d_in[2];
  const float* b_qkv = (const float*)d_in[3];
  const float* W_out = (const float*)d_in[4];
  const float* b_out = (const float*)d_in[5];
  const float* proj  = (const float*)d_in[6];
  float* out = (float*)d_out;

  float* ws     = (float*)d_ws;
  float* phases = ws;                      // NT*PH        = 2,097,152 floats
  float* qkv    = ws + (size_t)NT * PH;    // NT*3072      = 12,582,912 floats
  float* aout   = qkv + (size_t)NT * D3;   // NT*1024      = 4,194,304 floats
  // total ws: 75.5 MB

  // phases = p @ proj  (NN, 4096x512x1024)
  gemm_nn_64<<<dim3(PH / 64, NT / 64), 256, 0, stream>>>(p, proj, phases, Dd, PH);
  // qkv = x @ W_qkv^T + b_qkv  (NT x 3072, K=1024)
  gemm_nt_128<<<dim3(D3 / 128, NT / 128), 256, 0, stream>>>(x, W_qkv, b_qkv, qkv, Dd, D3);
  // rotate q,k in place
  rot_kernel<<<dim3((NT * Hh * 32) / 256), 256, 0, stream>>>(phases, qkv);
  // attention -> aout (B,L,D)
  attn_kernel<<<dim3(Ll / 64, Bb * Hh), 256, 0, stream>>>(qkv, aout);
  // out = aout @ W_out^T + b_out  (NT x 1024, K=1024)
  gemm_nt_128<<<dim3(Dd / 128, NT / 128), 256, 0, stream>>>(aout, W_out, b_out, out, Dd, Dd);
}

// Round 2
// 699.205 us; speedup vs baseline: 1.7028x; 1.7028x over previous
//
#include <hip/hip_runtime.h>
#include <hip/hip_bf16.h>
#include <math.h>

namespace {
constexpr int Bb = 2;
constexpr int Ll = 2048;
constexpr int Dd = 1024;
constexpr int Hh = 16;
constexpr int NT = Bb * Ll;   // 4096 tokens
constexpr int D3 = 3 * Dd;    // 3072
constexpr int PH = Dd / 2;    // 512 phases per token
constexpr int LDK = 72;       // LDS row stride in bf16 (64 + 8 pad, 144B rows, 16B aligned)
}

typedef __attribute__((ext_vector_type(8))) short bf16x8;
typedef __attribute__((ext_vector_type(4))) float f32x4;

__device__ inline unsigned pack2bf(float a, float b) {
  __hip_bfloat162 t = __float22bfloat162_rn(float2{a, b});
  union { __hip_bfloat162 h; unsigned u; } cv; cv.h = t;
  return cv.u;
}

// ---------------- fp32 GEMMs (unchanged from passing R1) ----------------

// C[n,m] = bias[m] + sum_k A[n,k] * W[m,k]
__global__ __launch_bounds__(256) void gemm_nt_128(
    const float* __restrict__ A, const float* __restrict__ W,
    const float* __restrict__ bias, float* __restrict__ C,
    int K, int M)
{
  constexpr int BK = 16;
  __shared__ float As[BK][132];
  __shared__ float Ws[BK][132];
  const int tid = threadIdx.x;
  const int m0 = blockIdx.x * 128;
  const int n0 = blockIdx.y * 128;
  const int ty = tid >> 4, tx = tid & 15;
  const int lrow = tid >> 2, lseg = tid & 3;

  float acc[8][8];
#pragma unroll
  for (int i = 0; i < 8; ++i)
#pragma unroll
    for (int j = 0; j < 8; ++j) acc[i][j] = 0.f;

  for (int k0 = 0; k0 < K; k0 += BK) {
#pragma unroll
    for (int r = 0; r < 2; ++r) {
      const int row = lrow + r * 64;
      const float4 av = *(const float4*)(A + (n0 + row) * K + k0 + lseg * 4);
      As[lseg*4+0][row] = av.x; As[lseg*4+1][row] = av.y;
      As[lseg*4+2][row] = av.z; As[lseg*4+3][row] = av.w;
      const float4 wv = *(const float4*)(W + (m0 + row) * K + k0 + lseg * 4);
      Ws[lseg*4+0][row] = wv.x; Ws[lseg*4+1][row] = wv.y;
      Ws[lseg*4+2][row] = wv.z; Ws[lseg*4+3][row] = wv.w;
    }
    __syncthreads();
#pragma unroll
    for (int kk = 0; kk < BK; ++kk) {
      const float4 a0 = *(const float4*)&As[kk][ty*8];
      const float4 a1 = *(const float4*)&As[kk][ty*8+4];
      const float4 b0 = *(const float4*)&Ws[kk][tx*8];
      const float4 b1 = *(const float4*)&Ws[kk][tx*8+4];
      const float a[8] = {a0.x,a0.y,a0.z,a0.w,a1.x,a1.y,a1.z,a1.w};
      const float b[8] = {b0.x,b0.y,b0.z,b0.w,b1.x,b1.y,b1.z,b1.w};
#pragma unroll
      for (int i = 0; i < 8; ++i)
#pragma unroll
        for (int j = 0; j < 8; ++j) acc[i][j] = fmaf(a[i], b[j], acc[i][j]);
    }
    __syncthreads();
  }
  float bv[8];
#pragma unroll
  for (int j = 0; j < 8; ++j) bv[j] = bias[m0 + tx*8 + j];
#pragma unroll
  for (int i = 0; i < 8; ++i) {
    float* crow = C + (n0 + ty*8 + i) * M + m0 + tx*8;
    *(float4*)(crow)     = make_float4(acc[i][0]+bv[0], acc[i][1]+bv[1],
                                       acc[i][2]+bv[2], acc[i][3]+bv[3]);
    *(float4*)(crow + 4) = make_float4(acc[i][4]+bv[4], acc[i][5]+bv[5],
                                       acc[i][6]+bv[6], acc[i][7]+bv[7]);
  }
}

// C[n,m] = sum_k A[n,k] * Bm[k,m]
__global__ __launch_bounds__(256) void gemm_nn_64(
    const float* __restrict__ A, const float* __restrict__ Bm,
    float* __restrict__ C, int K, int M)
{
  constexpr int BK = 32;
  __shared__ float As[BK][68];
  __shared__ float Bs[BK][68];
  const int tid = threadIdx.x;
  const int m0 = blockIdx.x * 64;
  const int n0 = blockIdx.y * 64;
  const int ty = tid >> 4, tx = tid & 15;

  float acc[4][4];
#pragma unroll
  for (int i = 0; i < 4; ++i)
#pragma unroll
    for (int j = 0; j < 4; ++j) acc[i][j] = 0.f;

  for (int k0 = 0; k0 < K; k0 += BK) {
#pragma unroll
    for (int r = 0; r < 2; ++r) {
      const int idx = r * 256 + tid;
      const int ar = idx >> 3, as = idx & 7;
      const float4 av = *(const float4*)(A + (n0 + ar) * K + k0 + as * 4);
      As[as*4+0][ar] = av.x; As[as*4+1][ar] = av.y;
      As[as*4+2][ar] = av.z; As[as*4+3][ar] = av.w;
      const int br = idx >> 4, bs = idx & 15;
      *(float4*)&Bs[br][bs*4] = *(const float4*)(Bm + (k0 + br) * M + m0 + bs * 4);
    }
    __syncthreads();
#pragma unroll
    for (int kk = 0; kk < BK; ++kk) {
      const float4 a4 = *(const float4*)&As[kk][ty*4];
      const float4 b4 = *(const float4*)&Bs[kk][tx*4];
      const float a[4] = {a4.x,a4.y,a4.z,a4.w};
      const float b[4] = {b4.x,b4.y,b4.z,b4.w};
#pragma unroll
      for (int i = 0; i < 4; ++i)
#pragma unroll
        for (int j = 0; j < 4; ++j) acc[i][j] = fmaf(a[i], b[j], acc[i][j]);
    }
    __syncthreads();
  }
#pragma unroll
  for (int i = 0; i < 4; ++i) {
    *(float4*)(C + (n0 + ty*4 + i) * M + m0 + tx*4) =
        make_float4(acc[i][0], acc[i][1], acc[i][2], acc[i][3]);
  }
}

// ---------------- rotary + cast to bf16 ----------------
// Reads fp32 qkv (unrotated), writes rotated q (scaled by log2e/8) and k as bf16
// in [token][H*64] layout. One thread per (token, head, i<32).
__global__ __launch_bounds__(256) void rot_cast_kernel(
    const float* __restrict__ phases, const float* __restrict__ qkv,
    __hip_bfloat16* __restrict__ q_bf, __hip_bfloat16* __restrict__ k_bf)
{
  const int gid = blockIdx.x * 256 + threadIdx.x;   // NT*H*32 = 2M
  const int i = gid & 31;
  const int h = (gid >> 5) & 15;
  const int n = gid >> 9;
  const float ph = phases[n * PH + h * 32 + i];
  float sn, cs;
  sincosf(ph, &sn, &cs);
  const int base = n * D3 + h * 64 + i;
  const float q1 = qkv[base], q2 = qkv[base + 32];
  const float k1 = qkv[base + Dd], k2 = qkv[base + Dd + 32];
  const float SC = 0.18033688011112042f;   // (1/8) * log2(e): exp2-domain scores
  const int ob = n * Dd + h * 64 + i;
  q_bf[ob]      = __float2bfloat16((q1 * cs - q2 * sn) * SC);
  q_bf[ob + 32] = __float2bfloat16((q1 * sn + q2 * cs) * SC);
  k_bf[ob]      = __float2bfloat16(k1 * cs - k2 * sn);
  k_bf[ob + 32] = __float2bfloat16(k1 * sn + k2 * cs);
}

// ---------------- V transpose + cast: qkv v-part -> vt_g[bh][d=64][tok=2048] bf16 ----
__global__ __launch_bounds__(256) void vtrans_kernel(
    const float* __restrict__ qkv, __hip_bfloat16* __restrict__ vt_g)
{
  __shared__ __align__(16) short Vl[64 * LDK];
  const int tid = threadIdx.x;
  const int tt = blockIdx.x;      // token tile (64 tokens)
  const int bh = blockIdx.y;
  const int b = bh >> 4, h = bh & 15;

  {
    const int tok = tid >> 2, ds = tid & 3;   // 16 d per thread
    const float* src = qkv + (size_t)(b * Ll + tt * 64 + tok) * D3 + 2 * Dd + h * 64 + ds * 16;
    unsigned* dstw = (unsigned*)&Vl[tok * LDK + ds * 16];
#pragma unroll
    for (int jj = 0; jj < 4; ++jj) {
      const float4 f = *(const float4*)(src + jj * 4);
      dstw[jj*2]   = pack2bf(f.x, f.y);
      dstw[jj*2+1] = pack2bf(f.z, f.w);
    }
  }
  __syncthreads();
  {
    const int d = tid >> 2, seg = tid & 3;    // 16 tokens per thread
    unsigned ow[8];
#pragma unroll
    for (int j = 0; j < 8; ++j) {
      const unsigned short a = (unsigned short)Vl[(seg*16 + 2*j)     * LDK + d];
      const unsigned short c = (unsigned short)Vl[(seg*16 + 2*j + 1) * LDK + d];
      ow[j] = (unsigned)a | ((unsigned)c << 16);
    }
    unsigned* dst = (unsigned*)(vt_g + ((size_t)(bh * 64 + d)) * Ll + tt * 64 + seg * 16);
    *(uint4*)(dst)     = make_uint4(ow[0], ow[1], ow[2], ow[3]);
    *(uint4*)(dst + 4) = make_uint4(ow[4], ow[5], ow[6], ow[7]);
  }
}

// ---------------- bf16 MFMA flash attention ----------------
// Q-tile 128, K-tile 64, 256 threads (4 waves). Wave w owns q columns w*32..w*32+31
// (2 groups of 16). S^T = K·Q^T so stats are per-lane (q = l&15 within group).
// P round-trips LDS (C-layout -> A-layout, m120 pattern). V from pre-transposed vt_g.
__global__ __launch_bounds__(256) void attn_mfma(
    const __hip_bfloat16* __restrict__ q_bf,
    const __hip_bfloat16* __restrict__ k_bf,
    const __hip_bfloat16* __restrict__ vt_g,
    float* __restrict__ aout)
{
  __shared__ __align__(16) short Ks[64 * LDK];   // K tile [kt][d]
  __shared__ __align__(16) short Vt[64 * LDK];   // V tile [d][kt]
  __shared__ __align__(16) short Ps[128 * LDK];  // P [q][kt], rows wave-private

  const int tid = threadIdx.x;
  const int w = tid >> 6;
  const int lane = tid & 63;
  const int l15 = lane & 15;
  const int quad = lane >> 4;

  const int q0 = blockIdx.x * 128;
  const int bh = blockIdx.y;
  const int b = bh >> 4, h = bh & 15;

  // Q fragments in registers for the whole kernel: qfrag[qg][kh]
  bf16x8 qfrag[2][2];
#pragma unroll
  for (int qg = 0; qg < 2; ++qg)
#pragma unroll
    for (int kh = 0; kh < 2; ++kh) {
      const size_t row = (size_t)(b * Ll + q0 + w * 32 + qg * 16 + l15);
      qfrag[qg][kh] = *(const bf16x8*)(q_bf + row * Dd + h * 64 + kh * 32 + quad * 8);
    }

  f32x4 acc_o[4][2];   // [dtile][qg]: O[q=w*32+qg*16+quad*4+r][d=dt*16+l15]
#pragma unroll
  for (int dt = 0; dt < 4; ++dt)
#pragma unroll
    for (int qg = 0; qg < 2; ++qg) acc_o[dt][qg] = f32x4{0.f, 0.f, 0.f, 0.f};
  float m_[2] = {-3e38f, -3e38f};
  float l_[2] = {0.f, 0.f};

  const int srow = tid >> 2, sseg = tid & 3;

  for (int kt = 0; kt < Ll / 64; ++kt) {
    __syncthreads();   // previous tile's reads of Ks/Vt complete
    {
      const uint4* kg = (const uint4*)(k_bf + (size_t)(b * Ll + kt * 64 + srow) * Dd + h * 64 + sseg * 16);
      *(uint4*)&Ks[srow * LDK + sseg * 16]     = kg[0];
      *(uint4*)&Ks[srow * LDK + sseg * 16 + 8] = kg[1];
      const uint4* vg = (const uint4*)(vt_g + ((size_t)(bh * 64 + srow)) * Ll + kt * 64 + sseg * 16);
      *(uint4*)&Vt[srow * LDK + sseg * 16]     = vg[0];
      *(uint4*)&Vt[srow * LDK + sseg * 16 + 8] = vg[1];
    }
    __syncthreads();

    // S^T strips: s[n][qg], rows kt = n*16+quad*4+r, col q = w*32+qg*16+l15
    f32x4 s[4][2];
#pragma unroll
    for (int n = 0; n < 4; ++n)
#pragma unroll
      for (int qg = 0; qg < 2; ++qg) s[n][qg] = f32x4{0.f, 0.f, 0.f, 0.f};
#pragma unroll
    for (int n = 0; n < 4; ++n) {
#pragma unroll
      for (int kh = 0; kh < 2; ++kh) {
        const bf16x8 af = *(const bf16x8*)&Ks[(n * 16 + l15) * LDK + kh * 32 + quad * 8];
        s[n][0] = __builtin_amdgcn_mfma_f32_16x16x32_bf16(af, qfrag[0][kh], s[n][0], 0, 0, 0);
        s[n][1] = __builtin_amdgcn_mfma_f32_16x16x32_bf16(af, qfrag[1][kh], s[n][1], 0, 0, 0);
      }
    }

    // online softmax (exp2 domain; scale folded into Q)
    float alpha[2];
#pragma unroll
    for (int qg = 0; qg < 2; ++qg) {
      float tm = -3e38f;
#pragma unroll
      for (int n = 0; n < 4; ++n)
#pragma unroll
        for (int r = 0; r < 4; ++r) tm = fmaxf(tm, s[n][qg][r]);
      tm = fmaxf(tm, __shfl_xor(tm, 16));
      tm = fmaxf(tm, __shfl_xor(tm, 32));
      const float mnew = fmaxf(m_[qg], tm);
      const float al = __builtin_amdgcn_exp2f(m_[qg] - mnew);
      m_[qg] = mnew; alpha[qg] = al;
      float rs = 0.f;
#pragma unroll
      for (int n = 0; n < 4; ++n)
#pragma unroll
        for (int r = 0; r < 4; ++r) {
          const float p = __builtin_amdgcn_exp2f(s[n][qg][r] - mnew);
          s[n][qg][r] = p; rs += p;
        }
      rs += __shfl_xor(rs, 16);
      rs += __shfl_xor(rs, 32);
      l_[qg] = l_[qg] * al + rs;

      // pack P to bf16, write to Ps[q][kt] (A-operand layout for PV)
      const int qrow = w * 32 + qg * 16 + l15;
      unsigned* prow = (unsigned*)&Ps[qrow * LDK];
#pragma unroll
      for (int n = 0; n < 4; ++n) {
        prow[n * 8 + quad * 2]     = pack2bf(s[n][qg][0], s[n][qg][1]);
        prow[n * 8 + quad * 2 + 1] = pack2bf(s[n][qg][2], s[n][qg][3]);
      }
    }

    // rescale O by alpha (gather per-row alpha from stat lanes)
#pragma unroll
    for (int qg = 0; qg < 2; ++qg)
#pragma unroll
      for (int r = 0; r < 4; ++r) {
        const float av = __shfl(alpha[qg], quad * 4 + r);
#pragma unroll
        for (int dt = 0; dt < 4; ++dt) acc_o[dt][qg][r] *= av;
      }

    // wave-private P write -> read hazard: drain LDS queue (cross-lane, same wave)
    asm volatile("s_waitcnt lgkmcnt(0)" ::: "memory");

    // O += P·V
#pragma unroll
    for (int kh = 0; kh < 2; ++kh) {
      bf16x8 pa[2];
      pa[0] = *(const bf16x8*)&Ps[(w * 32 + l15) * LDK + kh * 32 + quad * 8];
      pa[1] = *(const bf16x8*)&Ps[(w * 32 + 16 + l15) * LDK + kh * 32 + quad * 8];
#pragma unroll
      for (int dt = 0; dt < 4; ++dt) {
        const bf16x8 vb = *(const bf16x8*)&Vt[(dt * 16 + l15) * LDK + kh * 32 + quad * 8];
        acc_o[dt][0] = __builtin_amdgcn_mfma_f32_16x16x32_bf16(pa[0], vb, acc_o[dt][0], 0, 0, 0);
        acc_o[dt][1] = __builtin_amdgcn_mfma_f32_16x16x32_bf16(pa[1], vb, acc_o[dt][1], 0, 0, 0);
      }
    }
  }

  // epilogue: normalize and store fp32
#pragma unroll
  for (int qg = 0; qg < 2; ++qg)
#pragma unroll
    for (int r = 0; r < 4; ++r) {
      const float lv = __shfl(l_[qg], quad * 4 + r);
      const float linv = 1.f / lv;
      float* dst = aout + (size_t)(b * Ll + q0 + w * 32 + qg * 16 + quad * 4 + r) * Dd + h * 64 + l15;
#pragma unroll
      for (int dt = 0; dt < 4; ++dt) dst[dt * 16] = acc_o[dt][qg][r] * linv;
    }
}

extern "C" void kernel_launch(void* const* d_in, const int* in_sizes, int n_in,
                              void* d_out, int out_size, void* d_ws, size_t ws_size,
                              hipStream_t stream) {
  const float* x     = (const float*)d_in[0];
  const float* p     = (const float*)d_in[1];
  const float* W_qkv = (const float*)d_in[2];
  const float* b_qkv = (const float*)d_in[3];
  const float* W_out = (const float*)d_in[4];
  const float* b_out = (const float*)d_in[5];
  const float* proj  = (const float*)d_in[6];
  float* out = (float*)d_out;

  // workspace overlay (72 MB total, fits the 75.5 MB footprint of R1):
  //  [0,8M):    phases fp32 (consumed by rot_cast)  ->  then vt_g bf16 [32][64][2048]
  //  [8M,56M):  qkv fp32 (q,k dead after rot_cast; v dead after vtrans)
  //             first 16 MB reused as aout fp32 by attn
  //  [56M,64M): q_bf bf16 [NT][1024]
  //  [64M,72M): k_bf bf16 [NT][1024]
  char* wsb = (char*)d_ws;
  float*          phases = (float*)(wsb);
  __hip_bfloat16* vt_g   = (__hip_bfloat16*)(wsb);
  float*          qkv    = (float*)(wsb + 8388608);
  float*          aout   = (float*)(wsb + 8388608);
  __hip_bfloat16* q_bf   = (__hip_bfloat16*)(wsb + 58720256);
  __hip_bfloat16* k_bf   = (__hip_bfloat16*)(wsb + 67108864);

  // phases = p @ proj
  gemm_nn_64<<<dim3(PH / 64, NT / 64), 256, 0, stream>>>(p, proj, phases, Dd, PH);
  // qkv = x @ W_qkv^T + b_qkv
  gemm_nt_128<<<dim3(D3 / 128, NT / 128), 256, 0, stream>>>(x, W_qkv, b_qkv, qkv, Dd, D3);
  // rotate q,k -> bf16 (reads phases; must precede vtrans which overwrites phases)
  rot_cast_kernel<<<dim3((NT * Hh * 32) / 256), 256, 0, stream>>>(phases, qkv, q_bf, k_bf);
  // v -> transposed bf16 vt_g (overwrites phases region)
  vtrans_kernel<<<dim3(Ll / 64, Bb * Hh), 256, 0, stream>>>(qkv, vt_g);
  // flash attention (writes aout over dead qkv head)
  attn_mfma<<<dim3(Ll / 128, Bb * Hh), 256, 0, stream>>>(q_bf, k_bf, vt_g, aout);
  // out = aout @ W_out^T + b_out
  gemm_nt_128<<<dim3(Dd / 128, NT / 128), 256, 0, stream>>>(aout, W_out, b_out, out, Dd, Dd);
}

// Round 3
// 334.639 us; speedup vs baseline: 3.5579x; 2.0894x over previous
//
#include <hip/hip_runtime.h>
#include <hip/hip_bf16.h>
#include <math.h>

namespace {
constexpr int Bb = 2;
constexpr int Ll = 2048;
constexpr int Dd = 1024;
constexpr int Hh = 16;
constexpr int NT = Bb * Ll;   // 4096 tokens
constexpr int D3 = 3 * Dd;    // 3072
constexpr int PH = Dd / 2;    // 512 phases per token
constexpr int LDK = 72;       // LDS row stride (bf16) for attn tiles
}

typedef __attribute__((ext_vector_type(8))) short bf16x8;
typedef __attribute__((ext_vector_type(4))) float f32x4;

__device__ inline unsigned pack2bf(float a, float b) {
  __hip_bfloat162 t = __float22bfloat162_rn(float2{a, b});
  union { __hip_bfloat162 h; unsigned u; } cv; cv.h = t;
  return cv.u;
}

__device__ inline void async_cp16(const void* gsrc, void* ldst) {
  __builtin_amdgcn_global_load_lds(
      (const __attribute__((address_space(1))) unsigned int*)gsrc,
      (__attribute__((address_space(3))) unsigned int*)ldst, 16, 0, 0);
}

// ---------------- fp32 -> bf16 cast (packed) ----------------
__global__ __launch_bounds__(256) void cast4_kernel(
    const float4* __restrict__ src, uint2* __restrict__ dst, int n4)
{
  const int i = blockIdx.x * 256 + threadIdx.x;
  if (i >= n4) return;
  const float4 f = src[i];
  dst[i] = make_uint2(pack2bf(f.x, f.y), pack2bf(f.z, f.w));
}

// ---------------- bf16 MFMA GEMM:  C[n,m] = bias[m] + sum_k A[n,k]*W[m,k] ----------
// A: N x K bf16 row-major, W: M x K bf16 row-major, C fp32. 128x128 tile, BK=32,
// global_load_lds(16B) staging, XOR-swizzled unpadded LDS, 4 waves in 2x2.
__global__ __launch_bounds__(256) void gemm_bt_bf16(
    const __hip_bfloat16* __restrict__ A, const __hip_bfloat16* __restrict__ W,
    const float* __restrict__ bias, float* __restrict__ C, int K, int M)
{
  __shared__ __align__(16) short As[128 * 32];
  __shared__ __align__(16) short Ws[128 * 32];
  const int tid = threadIdx.x;
  const int w = tid >> 6, lane = tid & 63;
  const int l15 = lane & 15, quad = lane >> 4;
  const int wn = w >> 1, wm = w & 1;
  const int n0 = blockIdx.y * 128, m0 = blockIdx.x * 128;

  // staging: row = tid>>2 (0..63, +64 for second issue), chunk c = tid&3 (8 bf16 each)
  const int row = tid >> 2, cc = tid & 3;
  const int ksw = (cc ^ (row & 3)) * 8;          // XOR swizzle (row+64 has same row&3)
  const short* gA  = (const short*)A + (size_t)(n0 + row) * K + ksw;
  const short* gW  = (const short*)W + (size_t)(m0 + row) * K + ksw;
  short* lA  = As + tid * 8;                     // firstlane -> wave-uniform base
  short* lA2 = As + 2048 + tid * 8;
  short* lW  = Ws + tid * 8;
  short* lW2 = Ws + 2048 + tid * 8;

  f32x4 acc[4][4];
#pragma unroll
  for (int i = 0; i < 4; ++i)
#pragma unroll
    for (int j = 0; j < 4; ++j) acc[i][j] = f32x4{0.f, 0.f, 0.f, 0.f};

  const int swq = (quad ^ (l15 & 3)) * 8;        // frag-read swizzle

  for (int k0 = 0; k0 < K; k0 += 32) {
    __syncthreads();
    async_cp16(gA + k0, lA);
    async_cp16(gA + 64 * K + k0, lA2);
    async_cp16(gW + k0, lW);
    async_cp16(gW + 64 * K + k0, lW2);
    __syncthreads();

    bf16x8 af[4], bf[4];
#pragma unroll
    for (int i = 0; i < 4; ++i)
      af[i] = *(const bf16x8*)&As[(wn * 64 + i * 16 + l15) * 32 + swq];
#pragma unroll
    for (int j = 0; j < 4; ++j)
      bf[j] = *(const bf16x8*)&Ws[(wm * 64 + j * 16 + l15) * 32 + swq];
#pragma unroll
    for (int i = 0; i < 4; ++i)
#pragma unroll
      for (int j = 0; j < 4; ++j)
        acc[i][j] = __builtin_amdgcn_mfma_f32_16x16x32_bf16(af[i], bf[j], acc[i][j], 0, 0, 0);
  }

  float bv[4];
#pragma unroll
  for (int j = 0; j < 4; ++j) bv[j] = bias[m0 + wm * 64 + j * 16 + l15];
#pragma unroll
  for (int i = 0; i < 4; ++i)
#pragma unroll
    for (int r = 0; r < 4; ++r) {
      float* crow = C + (size_t)(n0 + wn * 64 + i * 16 + quad * 4 + r) * M + m0 + wm * 64 + l15;
#pragma unroll
      for (int j = 0; j < 4; ++j) crow[j * 16] = acc[i][j][r] + bv[j];
    }
}

// ---------------- fp32 GEMM NN (phases = p @ proj) — accuracy-critical, keep fp32 ---
__global__ __launch_bounds__(256) void gemm_nn_64(
    const float* __restrict__ A, const float* __restrict__ Bm,
    float* __restrict__ C, int K, int M)
{
  constexpr int BK = 32;
  __shared__ float As[BK][68];
  __shared__ float Bs[BK][68];
  const int tid = threadIdx.x;
  const int m0 = blockIdx.x * 64;
  const int n0 = blockIdx.y * 64;
  const int ty = tid >> 4, tx = tid & 15;

  float acc[4][4];
#pragma unroll
  for (int i = 0; i < 4; ++i)
#pragma unroll
    for (int j = 0; j < 4; ++j) acc[i][j] = 0.f;

  for (int k0 = 0; k0 < K; k0 += BK) {
#pragma unroll
    for (int r = 0; r < 2; ++r) {
      const int idx = r * 256 + tid;
      const int ar = idx >> 3, as = idx & 7;
      const float4 av = *(const float4*)(A + (n0 + ar) * K + k0 + as * 4);
      As[as*4+0][ar] = av.x; As[as*4+1][ar] = av.y;
      As[as*4+2][ar] = av.z; As[as*4+3][ar] = av.w;
      const int br = idx >> 4, bs = idx & 15;
      *(float4*)&Bs[br][bs*4] = *(const float4*)(Bm + (k0 + br) * M + m0 + bs * 4);
    }
    __syncthreads();
#pragma unroll
    for (int kk = 0; kk < BK; ++kk) {
      const float4 a4 = *(const float4*)&As[kk][ty*4];
      const float4 b4 = *(const float4*)&Bs[kk][tx*4];
      const float a[4] = {a4.x,a4.y,a4.z,a4.w};
      const float b[4] = {b4.x,b4.y,b4.z,b4.w};
#pragma unroll
      for (int i = 0; i < 4; ++i)
#pragma unroll
        for (int j = 0; j < 4; ++j) acc[i][j] = fmaf(a[i], b[j], acc[i][j]);
    }
    __syncthreads();
  }
#pragma unroll
  for (int i = 0; i < 4; ++i) {
    *(float4*)(C + (n0 + ty*4 + i) * M + m0 + tx*4) =
        make_float4(acc[i][0], acc[i][1], acc[i][2], acc[i][3]);
  }
}

// ---------------- rotary + cast to bf16 ----------------
__global__ __launch_bounds__(256) void rot_cast_kernel(
    const float* __restrict__ phases, const float* __restrict__ qkv,
    __hip_bfloat16* __restrict__ q_bf, __hip_bfloat16* __restrict__ k_bf)
{
  const int gid = blockIdx.x * 256 + threadIdx.x;   // NT*H*32 = 2M
  const int i = gid & 31;
  const int h = (gid >> 5) & 15;
  const int n = gid >> 9;
  const float ph = phases[n * PH + h * 32 + i];
  float sn, cs;
  sincosf(ph, &sn, &cs);
  const int base = n * D3 + h * 64 + i;
  const float q1 = qkv[base], q2 = qkv[base + 32];
  const float k1 = qkv[base + Dd], k2 = qkv[base + Dd + 32];
  const float SC = 0.18033688011112042f;   // (1/8) * log2(e): exp2-domain scores
  const int ob = n * Dd + h * 64 + i;
  q_bf[ob]      = __float2bfloat16((q1 * cs - q2 * sn) * SC);
  q_bf[ob + 32] = __float2bfloat16((q1 * sn + q2 * cs) * SC);
  k_bf[ob]      = __float2bfloat16(k1 * cs - k2 * sn);
  k_bf[ob + 32] = __float2bfloat16(k1 * sn + k2 * cs);
}

// ---------------- V transpose + cast: qkv v-part -> vt_g[bh][d=64][tok=2048] bf16 ----
__global__ __launch_bounds__(256) void vtrans_kernel(
    const float* __restrict__ qkv, __hip_bfloat16* __restrict__ vt_g)
{
  __shared__ __align__(16) short Vl[64 * LDK];
  const int tid = threadIdx.x;
  const int tt = blockIdx.x;      // token tile (64 tokens)
  const int bh = blockIdx.y;
  const int b = bh >> 4, h = bh & 15;

  {
    const int tok = tid >> 2, ds = tid & 3;
    const float* src = qkv + (size_t)(b * Ll + tt * 64 + tok) * D3 + 2 * Dd + h * 64 + ds * 16;
    unsigned* dstw = (unsigned*)&Vl[tok * LDK + ds * 16];
#pragma unroll
    for (int jj = 0; jj < 4; ++jj) {
      const float4 f = *(const float4*)(src + jj * 4);
      dstw[jj*2]   = pack2bf(f.x, f.y);
      dstw[jj*2+1] = pack2bf(f.z, f.w);
    }
  }
  __syncthreads();
  {
    const int d = tid >> 2, seg = tid & 3;
    unsigned ow[8];
#pragma unroll
    for (int j = 0; j < 8; ++j) {
      const unsigned short a = (unsigned short)Vl[(seg*16 + 2*j)     * LDK + d];
      const unsigned short c = (unsigned short)Vl[(seg*16 + 2*j + 1) * LDK + d];
      ow[j] = (unsigned)a | ((unsigned)c << 16);
    }
    unsigned* dst = (unsigned*)(vt_g + ((size_t)(bh * 64 + d)) * Ll + tt * 64 + seg * 16);
    *(uint4*)(dst)     = make_uint4(ow[0], ow[1], ow[2], ow[3]);
    *(uint4*)(dst + 4) = make_uint4(ow[4], ow[5], ow[6], ow[7]);
  }
}

// ---------------- bf16 MFMA flash attention (R2, epilogue now bf16) ----------------
__global__ __launch_bounds__(256) void attn_mfma(
    const __hip_bfloat16* __restrict__ q_bf,
    const __hip_bfloat16* __restrict__ k_bf,
    const __hip_bfloat16* __restrict__ vt_g,
    __hip_bfloat16* __restrict__ aout)
{
  __shared__ __align__(16) short Ks[64 * LDK];
  __shared__ __align__(16) short Vt[64 * LDK];
  __shared__ __align__(16) short Ps[128 * LDK];

  const int tid = threadIdx.x;
  const int w = tid >> 6;
  const int lane = tid & 63;
  const int l15 = lane & 15;
  const int quad = lane >> 4;

  const int q0 = blockIdx.x * 128;
  const int bh = blockIdx.y;
  const int b = bh >> 4, h = bh & 15;

  bf16x8 qfrag[2][2];
#pragma unroll
  for (int qg = 0; qg < 2; ++qg)
#pragma unroll
    for (int kh = 0; kh < 2; ++kh) {
      const size_t row = (size_t)(b * Ll + q0 + w * 32 + qg * 16 + l15);
      qfrag[qg][kh] = *(const bf16x8*)(q_bf + row * Dd + h * 64 + kh * 32 + quad * 8);
    }

  f32x4 acc_o[4][2];
#pragma unroll
  for (int dt = 0; dt < 4; ++dt)
#pragma unroll
    for (int qg = 0; qg < 2; ++qg) acc_o[dt][qg] = f32x4{0.f, 0.f, 0.f, 0.f};
  float m_[2] = {-3e38f, -3e38f};
  float l_[2] = {0.f, 0.f};

  const int srow = tid >> 2, sseg = tid & 3;

  for (int kt = 0; kt < Ll / 64; ++kt) {
    __syncthreads();
    {
      const uint4* kg = (const uint4*)(k_bf + (size_t)(b * Ll + kt * 64 + srow) * Dd + h * 64 + sseg * 16);
      *(uint4*)&Ks[srow * LDK + sseg * 16]     = kg[0];
      *(uint4*)&Ks[srow * LDK + sseg * 16 + 8] = kg[1];
      const uint4* vg = (const uint4*)(vt_g + ((size_t)(bh * 64 + srow)) * Ll + kt * 64 + sseg * 16);
      *(uint4*)&Vt[srow * LDK + sseg * 16]     = vg[0];
      *(uint4*)&Vt[srow * LDK + sseg * 16 + 8] = vg[1];
    }
    __syncthreads();

    f32x4 s[4][2];
#pragma unroll
    for (int n = 0; n < 4; ++n)
#pragma unroll
      for (int qg = 0; qg < 2; ++qg) s[n][qg] = f32x4{0.f, 0.f, 0.f, 0.f};
#pragma unroll
    for (int n = 0; n < 4; ++n) {
#pragma unroll
      for (int kh = 0; kh < 2; ++kh) {
        const bf16x8 af = *(const bf16x8*)&Ks[(n * 16 + l15) * LDK + kh * 32 + quad * 8];
        s[n][0] = __builtin_amdgcn_mfma_f32_16x16x32_bf16(af, qfrag[0][kh], s[n][0], 0, 0, 0);
        s[n][1] = __builtin_amdgcn_mfma_f32_16x16x32_bf16(af, qfrag[1][kh], s[n][1], 0, 0, 0);
      }
    }

    float alpha[2];
#pragma unroll
    for (int qg = 0; qg < 2; ++qg) {
      float tm = -3e38f;
#pragma unroll
      for (int n = 0; n < 4; ++n)
#pragma unroll
        for (int r = 0; r < 4; ++r) tm = fmaxf(tm, s[n][qg][r]);
      tm = fmaxf(tm, __shfl_xor(tm, 16));
      tm = fmaxf(tm, __shfl_xor(tm, 32));
      const float mnew = fmaxf(m_[qg], tm);
      const float al = __builtin_amdgcn_exp2f(m_[qg] - mnew);
      m_[qg] = mnew; alpha[qg] = al;
      float rs = 0.f;
#pragma unroll
      for (int n = 0; n < 4; ++n)
#pragma unroll
        for (int r = 0; r < 4; ++r) {
          const float p = __builtin_amdgcn_exp2f(s[n][qg][r] - mnew);
          s[n][qg][r] = p; rs += p;
        }
      rs += __shfl_xor(rs, 16);
      rs += __shfl_xor(rs, 32);
      l_[qg] = l_[qg] * al + rs;

      const int qrow = w * 32 + qg * 16 + l15;
      unsigned* prow = (unsigned*)&Ps[qrow * LDK];
#pragma unroll
      for (int n = 0; n < 4; ++n) {
        prow[n * 8 + quad * 2]     = pack2bf(s[n][qg][0], s[n][qg][1]);
        prow[n * 8 + quad * 2 + 1] = pack2bf(s[n][qg][2], s[n][qg][3]);
      }
    }

#pragma unroll
    for (int qg = 0; qg < 2; ++qg)
#pragma unroll
      for (int r = 0; r < 4; ++r) {
        const float av = __shfl(alpha[qg], quad * 4 + r);
#pragma unroll
        for (int dt = 0; dt < 4; ++dt) acc_o[dt][qg][r] *= av;
      }

    asm volatile("s_waitcnt lgkmcnt(0)" ::: "memory");

#pragma unroll
    for (int kh = 0; kh < 2; ++kh) {
      bf16x8 pa[2];
      pa[0] = *(const bf16x8*)&Ps[(w * 32 + l15) * LDK + kh * 32 + quad * 8];
      pa[1] = *(const bf16x8*)&Ps[(w * 32 + 16 + l15) * LDK + kh * 32 + quad * 8];
#pragma unroll
      for (int dt = 0; dt < 4; ++dt) {
        const bf16x8 vb = *(const bf16x8*)&Vt[(dt * 16 + l15) * LDK + kh * 32 + quad * 8];
        acc_o[dt][0] = __builtin_amdgcn_mfma_f32_16x16x32_bf16(pa[0], vb, acc_o[dt][0], 0, 0, 0);
        acc_o[dt][1] = __builtin_amdgcn_mfma_f32_16x16x32_bf16(pa[1], vb, acc_o[dt][1], 0, 0, 0);
      }
    }
  }

#pragma unroll
  for (int qg = 0; qg < 2; ++qg)
#pragma unroll
    for (int r = 0; r < 4; ++r) {
      const float lv = __shfl(l_[qg], quad * 4 + r);
      const float linv = 1.f / lv;
      __hip_bfloat16* dst = aout + (size_t)(b * Ll + q0 + w * 32 + qg * 16 + quad * 4 + r) * Dd + h * 64 + l15;
#pragma unroll
      for (int dt = 0; dt < 4; ++dt) dst[dt * 16] = __float2bfloat16(acc_o[dt][qg][r] * linv);
    }
}

extern "C" void kernel_launch(void* const* d_in, const int* in_sizes, int n_in,
                              void* d_out, int out_size, void* d_ws, size_t ws_size,
                              hipStream_t stream) {
  const float* x     = (const float*)d_in[0];
  const float* p     = (const float*)d_in[1];
  const float* W_qkv = (const float*)d_in[2];
  const float* b_qkv = (const float*)d_in[3];
  const float* W_out = (const float*)d_in[4];
  const float* b_out = (const float*)d_in[5];
  const float* proj  = (const float*)d_in[6];
  float* out = (float*)d_out;

  // workspace overlay (exactly 72 MiB = 75,497,472 B, the proven footprint):
  //  [0,8Mi):   phases fp32 (dead after rot_cast)      -> vt_g bf16
  //  [8,56Mi):  qkv fp32 (dead after vtrans)           -> aout_bf [8,16Mi), wout_bf [16,18Mi)
  //  [56,64Mi): x_bf (dead after qkv GEMM)             -> q_bf
  //  [64,70Mi): wqkv_bf (dead after qkv GEMM)          -> k_bf [64,72Mi)
  char* wsb = (char*)d_ws;
  float*          phases  = (float*)(wsb);
  __hip_bfloat16* vt_g    = (__hip_bfloat16*)(wsb);
  float*          qkv     = (float*)(wsb + (8u << 20));
  __hip_bfloat16* aout_bf = (__hip_bfloat16*)(wsb + (8u << 20));
  __hip_bfloat16* wout_bf = (__hip_bfloat16*)(wsb + (16u << 20));
  __hip_bfloat16* x_bf    = (__hip_bfloat16*)(wsb + (56u << 20));
  __hip_bfloat16* q_bf    = (__hip_bfloat16*)(wsb + (56u << 20));
  __hip_bfloat16* wqkv_bf = (__hip_bfloat16*)(wsb + (64u << 20));
  __hip_bfloat16* k_bf    = (__hip_bfloat16*)(wsb + (64u << 20));

  // casts
  cast4_kernel<<<4096, 256, 0, stream>>>((const float4*)x, (uint2*)x_bf, 1048576);
  cast4_kernel<<<3072, 256, 0, stream>>>((const float4*)W_qkv, (uint2*)wqkv_bf, 786432);
  // phases = p @ proj (fp32 — accuracy-critical)
  gemm_nn_64<<<dim3(PH / 64, NT / 64), 256, 0, stream>>>(p, proj, phases, Dd, PH);
  // qkv = x @ W_qkv^T + b_qkv  (bf16 MFMA, fp32 out)
  gemm_bt_bf16<<<dim3(D3 / 128, NT / 128), 256, 0, stream>>>(x_bf, wqkv_bf, b_qkv, qkv, Dd, D3);
  // rotate q,k -> bf16 (reads phases, qkv fp32)
  rot_cast_kernel<<<dim3((NT * Hh * 32) / 256), 256, 0, stream>>>(phases, qkv, q_bf, k_bf);
  // v -> transposed bf16 (overwrites phases region)
  vtrans_kernel<<<dim3(Ll / 64, Bb * Hh), 256, 0, stream>>>(qkv, vt_g);
  // W_out cast (into dead qkv tail region)
  cast4_kernel<<<1024, 256, 0, stream>>>((const float4*)W_out, (uint2*)wout_bf, 262144);
  // flash attention -> aout bf16
  attn_mfma<<<dim3(Ll / 128, Bb * Hh), 256, 0, stream>>>(q_bf, k_bf, vt_g, aout_bf);
  // out = aout @ W_out^T + b_out (bf16 MFMA, fp32 out)
  gemm_bt_bf16<<<dim3(Dd / 128, NT / 128), 256, 0, stream>>>(aout_bf, wout_bf, b_out, out, Dd, Dd);
}

// Round 4
// 299.033 us; speedup vs baseline: 3.9815x; 1.1191x over previous
//
#include <hip/hip_runtime.h>
#include <hip/hip_bf16.h>
#include <math.h>

namespace {
constexpr int Bb = 2;
constexpr int Ll = 2048;
constexpr int Dd = 1024;
constexpr int Hh = 16;
constexpr int NT = Bb * Ll;   // 4096 tokens
constexpr int D3 = 3 * Dd;    // 3072
constexpr int PH = Dd / 2;    // 512 phases per token
constexpr int LDK = 72;       // LDS row stride (bf16) for attn tiles
}

typedef __attribute__((ext_vector_type(8))) short bf16x8;
typedef __attribute__((ext_vector_type(4))) float f32x4;

__device__ inline unsigned pack2bf(float a, float b) {
  __hip_bfloat162 t = __float22bfloat162_rn(float2{a, b});
  union { __hip_bfloat162 h; unsigned u; } cv; cv.h = t;
  return cv.u;
}

__device__ inline void async_cp16(const void* gsrc, void* ldst) {
  __builtin_amdgcn_global_load_lds(
      (const __attribute__((address_space(1))) unsigned int*)gsrc,
      (__attribute__((address_space(3))) unsigned int*)ldst, 16, 0, 0);
}

// ---------------- fp32 -> bf16 cast (packed) ----------------
__global__ __launch_bounds__(256) void cast4_kernel(
    const float4* __restrict__ src, uint2* __restrict__ dst, int n4)
{
  const int i = blockIdx.x * 256 + threadIdx.x;
  if (i >= n4) return;
  const float4 f = src[i];
  dst[i] = make_uint2(pack2bf(f.x, f.y), pack2bf(f.z, f.w));
}

// ---------------- fp32 -> hi/lo bf16 split cast ----------------
__global__ __launch_bounds__(256) void split_cast_kernel(
    const float4* __restrict__ src, uint2* __restrict__ hi, uint2* __restrict__ lo, int n4)
{
  const int i = blockIdx.x * 256 + threadIdx.x;
  if (i >= n4) return;
  const float4 f = src[i];
  float hf[4], lf[4];
  const float ff[4] = {f.x, f.y, f.z, f.w};
#pragma unroll
  for (int j = 0; j < 4; ++j) {
    const __hip_bfloat16 h = __float2bfloat16(ff[j]);
    hf[j] = __bfloat162float(h);
    lf[j] = ff[j] - hf[j];
  }
  hi[i] = make_uint2(pack2bf(hf[0], hf[1]), pack2bf(hf[2], hf[3]));
  lo[i] = make_uint2(pack2bf(lf[0], lf[1]), pack2bf(lf[2], lf[3]));
}

// ---------------- proj transpose + hi/lo split: [1024 d][512 m] -> [512 m][1024 d] ---
__global__ __launch_bounds__(256) void trans_split_kernel(
    const float* __restrict__ proj, short* __restrict__ th, short* __restrict__ tl)
{
  __shared__ float Ls[64][65];
  const int tid = threadIdx.x;
  const int d0 = blockIdx.x * 64, m0 = blockIdx.y * 64;
  const int r = tid >> 4, c4 = (tid & 15) * 4;
#pragma unroll
  for (int it = 0; it < 4; ++it) {
    const int row = it * 16 + r;
    const float4 v = *(const float4*)&proj[(size_t)(d0 + row) * PH + m0 + c4];
    Ls[row][c4] = v.x; Ls[row][c4+1] = v.y; Ls[row][c4+2] = v.z; Ls[row][c4+3] = v.w;
  }
  __syncthreads();
#pragma unroll
  for (int it = 0; it < 4; ++it) {
    const int row = it * 16 + r;   // output m-row (local)
    float hf[4], lf[4];
#pragma unroll
    for (int j = 0; j < 4; ++j) {
      const float v = Ls[c4 + j][row];
      const __hip_bfloat16 h = __float2bfloat16(v);
      hf[j] = __bfloat162float(h);
      lf[j] = v - hf[j];
    }
    *(uint2*)&th[(size_t)(m0 + row) * Dd + d0 + c4] = make_uint2(pack2bf(hf[0], hf[1]), pack2bf(hf[2], hf[3]));
    *(uint2*)&tl[(size_t)(m0 + row) * Dd + d0 + c4] = make_uint2(pack2bf(lf[0], lf[1]), pack2bf(lf[2], lf[3]));
  }
}

// ---------------- split-bf16 MFMA GEMM for phases --------------------------------
// C[n,m] = sum_k p[n,k]*proj[k,m] via hi/lo split: hh + hl + lh. 64x64 tile, BK=32.
// A (p) hi/lo: [4096][1024] bf16; W (proj^T) hi/lo: [512][1024] bf16. C fp32 [4096][512].
__global__ __launch_bounds__(256) void gemm_nn_split(
    const short* __restrict__ Ah_g, const short* __restrict__ Al_g,
    const short* __restrict__ Wh_g, const short* __restrict__ Wl_g,
    float* __restrict__ C)
{
  __shared__ __align__(16) short Ah[64 * 32], Al[64 * 32], Wh[64 * 32], Wl[64 * 32];
  const int tid = threadIdx.x;
  const int w = tid >> 6, lane = tid & 63;
  const int l15 = lane & 15, quad = lane >> 4;
  const int wn = w >> 1, wm = w & 1;
  const int n0 = blockIdx.y * 64, m0 = blockIdx.x * 64;

  const int row = tid >> 2, cc = tid & 3;
  const int ksw = (cc ^ (row & 3)) * 8;
  const short* gAh = Ah_g + (size_t)(n0 + row) * Dd + ksw;
  const short* gAl = Al_g + (size_t)(n0 + row) * Dd + ksw;
  const short* gWh = Wh_g + (size_t)(m0 + row) * Dd + ksw;
  const short* gWl = Wl_g + (size_t)(m0 + row) * Dd + ksw;
  short* lAh = Ah + tid * 8;
  short* lAl = Al + tid * 8;
  short* lWh = Wh + tid * 8;
  short* lWl = Wl + tid * 8;

  f32x4 acc[2][2];
#pragma unroll
  for (int i = 0; i < 2; ++i)
#pragma unroll
    for (int j = 0; j < 2; ++j) acc[i][j] = f32x4{0.f, 0.f, 0.f, 0.f};

  const int swq = (quad ^ (l15 & 3)) * 8;

  for (int k0 = 0; k0 < Dd; k0 += 32) {
    __syncthreads();
    async_cp16(gAh + k0, lAh);
    async_cp16(gAl + k0, lAl);
    async_cp16(gWh + k0, lWh);
    async_cp16(gWl + k0, lWl);
    __syncthreads();

    bf16x8 ah[2], al[2], wh[2], wl[2];
#pragma unroll
    for (int i = 0; i < 2; ++i) {
      ah[i] = *(const bf16x8*)&Ah[(wn * 32 + i * 16 + l15) * 32 + swq];
      al[i] = *(const bf16x8*)&Al[(wn * 32 + i * 16 + l15) * 32 + swq];
    }
#pragma unroll
    for (int j = 0; j < 2; ++j) {
      wh[j] = *(const bf16x8*)&Wh[(wm * 32 + j * 16 + l15) * 32 + swq];
      wl[j] = *(const bf16x8*)&Wl[(wm * 32 + j * 16 + l15) * 32 + swq];
    }
#pragma unroll
    for (int i = 0; i < 2; ++i)
#pragma unroll
      for (int j = 0; j < 2; ++j) {
        acc[i][j] = __builtin_amdgcn_mfma_f32_16x16x32_bf16(ah[i], wh[j], acc[i][j], 0, 0, 0);
        acc[i][j] = __builtin_amdgcn_mfma_f32_16x16x32_bf16(ah[i], wl[j], acc[i][j], 0, 0, 0);
        acc[i][j] = __builtin_amdgcn_mfma_f32_16x16x32_bf16(al[i], wh[j], acc[i][j], 0, 0, 0);
      }
  }

#pragma unroll
  for (int i = 0; i < 2; ++i)
#pragma unroll
    for (int r = 0; r < 4; ++r) {
      float* crow = C + (size_t)(n0 + wn * 32 + i * 16 + quad * 4 + r) * PH + m0 + wm * 32 + l15;
#pragma unroll
      for (int j = 0; j < 2; ++j) crow[j * 16] = acc[i][j][r];
    }
}

// ---------------- bf16 MFMA GEMM:  C[n,m] = bias[m] + sum_k A[n,k]*W[m,k] ----------
__global__ __launch_bounds__(256) void gemm_bt_bf16(
    const __hip_bfloat16* __restrict__ A, const __hip_bfloat16* __restrict__ W,
    const float* __restrict__ bias, float* __restrict__ C, int K, int M)
{
  __shared__ __align__(16) short As[128 * 32];
  __shared__ __align__(16) short Ws[128 * 32];
  const int tid = threadIdx.x;
  const int w = tid >> 6, lane = tid & 63;
  const int l15 = lane & 15, quad = lane >> 4;
  const int wn = w >> 1, wm = w & 1;
  const int n0 = blockIdx.y * 128, m0 = blockIdx.x * 128;

  const int row = tid >> 2, cc = tid & 3;
  const int ksw = (cc ^ (row & 3)) * 8;
  const short* gA  = (const short*)A + (size_t)(n0 + row) * K + ksw;
  const short* gW  = (const short*)W + (size_t)(m0 + row) * K + ksw;
  short* lA  = As + tid * 8;
  short* lA2 = As + 2048 + tid * 8;
  short* lW  = Ws + tid * 8;
  short* lW2 = Ws + 2048 + tid * 8;

  f32x4 acc[4][4];
#pragma unroll
  for (int i = 0; i < 4; ++i)
#pragma unroll
    for (int j = 0; j < 4; ++j) acc[i][j] = f32x4{0.f, 0.f, 0.f, 0.f};

  const int swq = (quad ^ (l15 & 3)) * 8;

  for (int k0 = 0; k0 < K; k0 += 32) {
    __syncthreads();
    async_cp16(gA + k0, lA);
    async_cp16(gA + 64 * K + k0, lA2);
    async_cp16(gW + k0, lW);
    async_cp16(gW + 64 * K + k0, lW2);
    __syncthreads();

    bf16x8 af[4], bf[4];
#pragma unroll
    for (int i = 0; i < 4; ++i)
      af[i] = *(const bf16x8*)&As[(wn * 64 + i * 16 + l15) * 32 + swq];
#pragma unroll
    for (int j = 0; j < 4; ++j)
      bf[j] = *(const bf16x8*)&Ws[(wm * 64 + j * 16 + l15) * 32 + swq];
#pragma unroll
    for (int i = 0; i < 4; ++i)
#pragma unroll
      for (int j = 0; j < 4; ++j)
        acc[i][j] = __builtin_amdgcn_mfma_f32_16x16x32_bf16(af[i], bf[j], acc[i][j], 0, 0, 0);
  }

  float bv[4];
#pragma unroll
  for (int j = 0; j < 4; ++j) bv[j] = bias[m0 + wm * 64 + j * 16 + l15];
#pragma unroll
  for (int i = 0; i < 4; ++i)
#pragma unroll
    for (int r = 0; r < 4; ++r) {
      float* crow = C + (size_t)(n0 + wn * 64 + i * 16 + quad * 4 + r) * M + m0 + wm * 64 + l15;
#pragma unroll
      for (int j = 0; j < 4; ++j) crow[j * 16] = acc[i][j][r] + bv[j];
    }
}

// ---------------- rotary + cast to bf16 ----------------
__global__ __launch_bounds__(256) void rot_cast_kernel(
    const float* __restrict__ phases, const float* __restrict__ qkv,
    __hip_bfloat16* __restrict__ q_bf, __hip_bfloat16* __restrict__ k_bf)
{
  const int gid = blockIdx.x * 256 + threadIdx.x;   // NT*H*32 = 2M
  const int i = gid & 31;
  const int h = (gid >> 5) & 15;
  const int n = gid >> 9;
  const float ph = phases[n * PH + h * 32 + i];
  float sn, cs;
  sincosf(ph, &sn, &cs);
  const int base = n * D3 + h * 64 + i;
  const float q1 = qkv[base], q2 = qkv[base + 32];
  const float k1 = qkv[base + Dd], k2 = qkv[base + Dd + 32];
  const float SC = 0.18033688011112042f;   // (1/8) * log2(e): exp2-domain scores
  const int ob = n * Dd + h * 64 + i;
  q_bf[ob]      = __float2bfloat16((q1 * cs - q2 * sn) * SC);
  q_bf[ob + 32] = __float2bfloat16((q1 * sn + q2 * cs) * SC);
  k_bf[ob]      = __float2bfloat16(k1 * cs - k2 * sn);
  k_bf[ob + 32] = __float2bfloat16(k1 * sn + k2 * cs);
}

// ---------------- V transpose + cast: qkv v-part -> vt_g[bh][d=64][tok=2048] bf16 ----
__global__ __launch_bounds__(256) void vtrans_kernel(
    const float* __restrict__ qkv, __hip_bfloat16* __restrict__ vt_g)
{
  __shared__ __align__(16) short Vl[64 * LDK];
  const int tid = threadIdx.x;
  const int tt = blockIdx.x;      // token tile (64 tokens)
  const int bh = blockIdx.y;
  const int b = bh >> 4, h = bh & 15;

  {
    const int tok = tid >> 2, ds = tid & 3;
    const float* src = qkv + (size_t)(b * Ll + tt * 64 + tok) * D3 + 2 * Dd + h * 64 + ds * 16;
    unsigned* dstw = (unsigned*)&Vl[tok * LDK + ds * 16];
#pragma unroll
    for (int jj = 0; jj < 4; ++jj) {
      const float4 f = *(const float4*)(src + jj * 4);
      dstw[jj*2]   = pack2bf(f.x, f.y);
      dstw[jj*2+1] = pack2bf(f.z, f.w);
    }
  }
  __syncthreads();
  {
    const int d = tid >> 2, seg = tid & 3;
    unsigned ow[8];
#pragma unroll
    for (int j = 0; j < 8; ++j) {
      const unsigned short a = (unsigned short)Vl[(seg*16 + 2*j)     * LDK + d];
      const unsigned short c = (unsigned short)Vl[(seg*16 + 2*j + 1) * LDK + d];
      ow[j] = (unsigned)a | ((unsigned)c << 16);
    }
    unsigned* dst = (unsigned*)(vt_g + ((size_t)(bh * 64 + d)) * Ll + tt * 64 + seg * 16);
    *(uint4*)(dst)     = make_uint4(ow[0], ow[1], ow[2], ow[3]);
    *(uint4*)(dst + 4) = make_uint4(ow[4], ow[5], ow[6], ow[7]);
  }
}

// ---------------- bf16 MFMA flash attention — Q-tile 64 (4x occupancy) --------------
// Block: 256 thr (4 waves), Q=64 (wave w owns q group w*16..w*16+15), K-tile 64.
// S^T = K·Q^T; P LDS round-trip; V pre-transposed. Grid 32x32 = 1024 blocks, 4/CU.
__global__ __launch_bounds__(256) void attn_mfma(
    const __hip_bfloat16* __restrict__ q_bf,
    const __hip_bfloat16* __restrict__ k_bf,
    const __hip_bfloat16* __restrict__ vt_g,
    __hip_bfloat16* __restrict__ aout)
{
  __shared__ __align__(16) short Ks[64 * LDK];
  __shared__ __align__(16) short Vt[64 * LDK];
  __shared__ __align__(16) short Ps[64 * LDK];

  const int tid = threadIdx.x;
  const int w = tid >> 6;
  const int lane = tid & 63;
  const int l15 = lane & 15;
  const int quad = lane >> 4;

  const int q0 = blockIdx.x * 64;
  const int bh = blockIdx.y;
  const int b = bh >> 4, h = bh & 15;

  bf16x8 qfrag[2];
#pragma unroll
  for (int kh = 0; kh < 2; ++kh) {
    const size_t qrow = (size_t)(b * Ll + q0 + w * 16 + l15);
    qfrag[kh] = *(const bf16x8*)(q_bf + qrow * Dd + h * 64 + kh * 32 + quad * 8);
  }

  f32x4 acc_o[4];
#pragma unroll
  for (int dt = 0; dt < 4; ++dt) acc_o[dt] = f32x4{0.f, 0.f, 0.f, 0.f};
  float m_ = -3e38f;
  float l_ = 0.f;

  const int srow = tid >> 2, sseg = tid & 3;
  const __hip_bfloat16* kbase = k_bf + (size_t)(b * Ll + srow) * Dd + h * 64 + sseg * 16;
  const __hip_bfloat16* vbase = vt_g + ((size_t)(bh * 64 + srow)) * Ll + sseg * 16;

  for (int kt = 0; kt < Ll / 64; ++kt) {
    __syncthreads();
    {
      const uint4* kg = (const uint4*)(kbase + (size_t)kt * 64 * Dd);
      *(uint4*)&Ks[srow * LDK + sseg * 16]     = kg[0];
      *(uint4*)&Ks[srow * LDK + sseg * 16 + 8] = kg[1];
      const uint4* vg = (const uint4*)(vbase + kt * 64);
      *(uint4*)&Vt[srow * LDK + sseg * 16]     = vg[0];
      *(uint4*)&Vt[srow * LDK + sseg * 16 + 8] = vg[1];
    }
    __syncthreads();

    f32x4 s[4];
#pragma unroll
    for (int n = 0; n < 4; ++n) s[n] = f32x4{0.f, 0.f, 0.f, 0.f};
#pragma unroll
    for (int n = 0; n < 4; ++n) {
#pragma unroll
      for (int kh = 0; kh < 2; ++kh) {
        const bf16x8 af = *(const bf16x8*)&Ks[(n * 16 + l15) * LDK + kh * 32 + quad * 8];
        s[n] = __builtin_amdgcn_mfma_f32_16x16x32_bf16(af, qfrag[kh], s[n], 0, 0, 0);
      }
    }

    // online softmax (exp2 domain)
    float tm = -3e38f;
#pragma unroll
    for (int n = 0; n < 4; ++n)
#pragma unroll
      for (int r = 0; r < 4; ++r) tm = fmaxf(tm, s[n][r]);
    tm = fmaxf(tm, __shfl_xor(tm, 16));
    tm = fmaxf(tm, __shfl_xor(tm, 32));
    const float mnew = fmaxf(m_, tm);
    const float al = __builtin_amdgcn_exp2f(m_ - mnew);
    m_ = mnew;
    float rs = 0.f;
#pragma unroll
    for (int n = 0; n < 4; ++n)
#pragma unroll
      for (int r = 0; r < 4; ++r) {
        const float pv = __builtin_amdgcn_exp2f(s[n][r] - mnew);
        s[n][r] = pv; rs += pv;
      }
    rs += __shfl_xor(rs, 16);
    rs += __shfl_xor(rs, 32);
    l_ = l_ * al + rs;

    // P pack -> Ps[q][kt] (A-operand layout), wave-private rows
    {
      unsigned* prow = (unsigned*)&Ps[(w * 16 + l15) * LDK];
#pragma unroll
      for (int n = 0; n < 4; ++n) {
        prow[n * 8 + quad * 2]     = pack2bf(s[n][0], s[n][1]);
        prow[n * 8 + quad * 2 + 1] = pack2bf(s[n][2], s[n][3]);
      }
    }

    // rescale O by alpha (per-row gather from stat lanes)
#pragma unroll
    for (int r = 0; r < 4; ++r) {
      const float av = __shfl(al, quad * 4 + r);
#pragma unroll
      for (int dt = 0; dt < 4; ++dt) acc_o[dt][r] *= av;
    }

    asm volatile("s_waitcnt lgkmcnt(0)" ::: "memory");

    // O += P·V
#pragma unroll
    for (int kh = 0; kh < 2; ++kh) {
      const bf16x8 pa = *(const bf16x8*)&Ps[(w * 16 + l15) * LDK + kh * 32 + quad * 8];
#pragma unroll
      for (int dt = 0; dt < 4; ++dt) {
        const bf16x8 vb = *(const bf16x8*)&Vt[(dt * 16 + l15) * LDK + kh * 32 + quad * 8];
        acc_o[dt] = __builtin_amdgcn_mfma_f32_16x16x32_bf16(pa, vb, acc_o[dt], 0, 0, 0);
      }
    }
  }

#pragma unroll
  for (int r = 0; r < 4; ++r) {
    const float lv = __shfl(l_, quad * 4 + r);
    const float linv = 1.f / lv;
    __hip_bfloat16* dst = aout + (size_t)(b * Ll + q0 + w * 16 + quad * 4 + r) * Dd + h * 64 + l15;
#pragma unroll
    for (int dt = 0; dt < 4; ++dt) dst[dt * 16] = __float2bfloat16(acc_o[dt][r] * linv);
  }
}

extern "C" void kernel_launch(void* const* d_in, const int* in_sizes, int n_in,
                              void* d_out, int out_size, void* d_ws, size_t ws_size,
                              hipStream_t stream) {
  const float* x     = (const float*)d_in[0];
  const float* p     = (const float*)d_in[1];
  const float* W_qkv = (const float*)d_in[2];
  const float* b_qkv = (const float*)d_in[3];
  const float* W_out = (const float*)d_in[4];
  const float* b_out = (const float*)d_in[5];
  const float* proj  = (const float*)d_in[6];
  float* out = (float*)d_out;

  // workspace overlay (72 MiB, proven footprint). Stream order makes reuse safe:
  //  [0,8Mi):   phases fp32 (dead after rot_cast)      -> vt_g bf16
  //  [8,56Mi):  PHASE A: p_hi [8,16), p_lo [16,24), projt_hi [24,25), projt_lo [25,26)
  //             PHASE B (after phases GEMM): qkv fp32
  //             PHASE C (after vtrans): aout_bf [8,16), wout_bf [16,18)
  //  [56,64Mi): x_bf (dead after qkv GEMM)             -> q_bf
  //  [64,72Mi): wqkv_bf (dead after qkv GEMM)          -> k_bf
  char* wsb = (char*)d_ws;
  float*          phases   = (float*)(wsb);
  __hip_bfloat16* vt_g     = (__hip_bfloat16*)(wsb);
  short*          p_hi     = (short*)(wsb + (8u << 20));
  short*          p_lo     = (short*)(wsb + (16u << 20));
  short*          projt_hi = (short*)(wsb + (24u << 20));
  short*          projt_lo = (short*)(wsb + (25u << 20));
  float*          qkv      = (float*)(wsb + (8u << 20));
  __hip_bfloat16* aout_bf  = (__hip_bfloat16*)(wsb + (8u << 20));
  __hip_bfloat16* wout_bf  = (__hip_bfloat16*)(wsb + (16u << 20));
  __hip_bfloat16* x_bf     = (__hip_bfloat16*)(wsb + (56u << 20));
  __hip_bfloat16* q_bf     = (__hip_bfloat16*)(wsb + (56u << 20));
  __hip_bfloat16* wqkv_bf  = (__hip_bfloat16*)(wsb + (64u << 20));
  __hip_bfloat16* k_bf     = (__hip_bfloat16*)(wsb + (64u << 20));

  // phases pipeline (split-bf16, fp32-grade accuracy at MFMA rate)
  split_cast_kernel<<<4096, 256, 0, stream>>>((const float4*)p, (uint2*)p_hi, (uint2*)p_lo, 1048576);
  trans_split_kernel<<<dim3(Dd / 64, PH / 64), 256, 0, stream>>>(proj, projt_hi, projt_lo);
  gemm_nn_split<<<dim3(PH / 64, NT / 64), 256, 0, stream>>>(p_hi, p_lo, projt_hi, projt_lo, phases);
  // qkv pipeline
  cast4_kernel<<<4096, 256, 0, stream>>>((const float4*)x, (uint2*)x_bf, 1048576);
  cast4_kernel<<<3072, 256, 0, stream>>>((const float4*)W_qkv, (uint2*)wqkv_bf, 786432);
  gemm_bt_bf16<<<dim3(D3 / 128, NT / 128), 256, 0, stream>>>(x_bf, wqkv_bf, b_qkv, qkv, Dd, D3);
  // rotate q,k -> bf16 (reads phases + fp32 qkv)
  rot_cast_kernel<<<dim3((NT * Hh * 32) / 256), 256, 0, stream>>>(phases, qkv, q_bf, k_bf);
  // v -> transposed bf16 (overwrites phases region)
  vtrans_kernel<<<dim3(Ll / 64, Bb * Hh), 256, 0, stream>>>(qkv, vt_g);
  // W_out cast (into dead qkv region)
  cast4_kernel<<<1024, 256, 0, stream>>>((const float4*)W_out, (uint2*)wout_bf, 262144);
  // flash attention -> aout bf16 (Q-tile 64, 1024 blocks)
  attn_mfma<<<dim3(Ll / 64, Bb * Hh), 256, 0, stream>>>(q_bf, k_bf, vt_g, aout_bf);
  // out = aout @ W_out^T + b_out
  gemm_bt_bf16<<<dim3(Dd / 128, NT / 128), 256, 0, stream>>>(aout_bf, wout_bf, b_out, out, Dd, Dd);
}

// Round 5
// 284.551 us; speedup vs baseline: 4.1842x; 1.0509x over previous
//
#include <hip/hip_runtime.h>
#include <hip/hip_bf16.h>
#include <math.h>

namespace {
constexpr int Bb = 2;
constexpr int Ll = 2048;
constexpr int Dd = 1024;
constexpr int Hh = 16;
constexpr int NT = Bb * Ll;   // 4096 tokens
constexpr int D3 = 3 * Dd;    // 3072
constexpr int PH = Dd / 2;    // 512 phases per token
constexpr int LDK = 72;       // LDS row stride (bf16) for attn tiles
}

typedef __attribute__((ext_vector_type(8))) short bf16x8;
typedef __attribute__((ext_vector_type(4))) short bf16x4;
typedef __attribute__((ext_vector_type(4))) float f32x4;

#if defined(__has_builtin)
#if __has_builtin(__builtin_amdgcn_mfma_f32_16x16x16bf16_1k)
#define HAVE_MFMA16 1
#endif
#endif

__device__ inline unsigned pack2bf(float a, float b) {
  __hip_bfloat162 t = __float22bfloat162_rn(float2{a, b});
  union { __hip_bfloat162 h; unsigned u; } cv; cv.h = t;
  return cv.u;
}

__device__ inline bf16x4 u2bf4(uint2 u) {
  union { uint2 u; bf16x4 v; } c; c.u = u; return c.v;
}

// PV matmul piece: D = V^T-frag (A) x P-frag (B) + C at K=16 granularity.
__device__ inline f32x4 pv_mfma(bf16x4 va, bf16x4 vb, f32x4 c) {
#ifdef HAVE_MFMA16
  return __builtin_amdgcn_mfma_f32_16x16x16bf16_1k(va, vb, c, 0, 0, 0);
#else
  // zero-padded K=32 fallback: effective k = quad*8 + j (j<4) <-> kt = quad*4 + j
  const bf16x8 a8 = {va[0], va[1], va[2], va[3], 0, 0, 0, 0};
  const bf16x8 b8 = {vb[0], vb[1], vb[2], vb[3], 0, 0, 0, 0};
  return __builtin_amdgcn_mfma_f32_16x16x32_bf16(a8, b8, c, 0, 0, 0);
#endif
}

__device__ inline void async_cp16(const void* gsrc, void* ldst) {
  __builtin_amdgcn_global_load_lds(
      (const __attribute__((address_space(1))) unsigned int*)gsrc,
      (__attribute__((address_space(3))) unsigned int*)ldst, 16, 0, 0);
}

// ---------------- fp32 -> bf16 cast (packed) ----------------
__global__ __launch_bounds__(256) void cast4_kernel(
    const float4* __restrict__ src, uint2* __restrict__ dst, int n4)
{
  const int i = blockIdx.x * 256 + threadIdx.x;
  if (i >= n4) return;
  const float4 f = src[i];
  dst[i] = make_uint2(pack2bf(f.x, f.y), pack2bf(f.z, f.w));
}

// ---------------- fp32 -> hi/lo bf16 split cast ----------------
__global__ __launch_bounds__(256) void split_cast_kernel(
    const float4* __restrict__ src, uint2* __restrict__ hi, uint2* __restrict__ lo, int n4)
{
  const int i = blockIdx.x * 256 + threadIdx.x;
  if (i >= n4) return;
  const float4 f = src[i];
  float hf[4], lf[4];
  const float ff[4] = {f.x, f.y, f.z, f.w};
#pragma unroll
  for (int j = 0; j < 4; ++j) {
    const __hip_bfloat16 h = __float2bfloat16(ff[j]);
    hf[j] = __bfloat162float(h);
    lf[j] = ff[j] - hf[j];
  }
  hi[i] = make_uint2(pack2bf(hf[0], hf[1]), pack2bf(hf[2], hf[3]));
  lo[i] = make_uint2(pack2bf(lf[0], lf[1]), pack2bf(lf[2], lf[3]));
}

// ---------------- proj transpose + hi/lo split: [1024 d][512 m] -> [512 m][1024 d] ---
__global__ __launch_bounds__(256) void trans_split_kernel(
    const float* __restrict__ proj, short* __restrict__ th, short* __restrict__ tl)
{
  __shared__ float Ls[64][65];
  const int tid = threadIdx.x;
  const int d0 = blockIdx.x * 64, m0 = blockIdx.y * 64;
  const int r = tid >> 4, c4 = (tid & 15) * 4;
#pragma unroll
  for (int it = 0; it < 4; ++it) {
    const int row = it * 16 + r;
    const float4 v = *(const float4*)&proj[(size_t)(d0 + row) * PH + m0 + c4];
    Ls[row][c4] = v.x; Ls[row][c4+1] = v.y; Ls[row][c4+2] = v.z; Ls[row][c4+3] = v.w;
  }
  __syncthreads();
#pragma unroll
  for (int it = 0; it < 4; ++it) {
    const int row = it * 16 + r;   // output m-row (local)
    float hf[4], lf[4];
#pragma unroll
    for (int j = 0; j < 4; ++j) {
      const float v = Ls[c4 + j][row];
      const __hip_bfloat16 h = __float2bfloat16(v);
      hf[j] = __bfloat162float(h);
      lf[j] = v - hf[j];
    }
    *(uint2*)&th[(size_t)(m0 + row) * Dd + d0 + c4] = make_uint2(pack2bf(hf[0], hf[1]), pack2bf(hf[2], hf[3]));
    *(uint2*)&tl[(size_t)(m0 + row) * Dd + d0 + c4] = make_uint2(pack2bf(lf[0], lf[1]), pack2bf(lf[2], lf[3]));
  }
}

// ---------------- split-bf16 MFMA GEMM for phases --------------------------------
__global__ __launch_bounds__(256) void gemm_nn_split(
    const short* __restrict__ Ah_g, const short* __restrict__ Al_g,
    const short* __restrict__ Wh_g, const short* __restrict__ Wl_g,
    float* __restrict__ C)
{
  __shared__ __align__(16) short Ah[64 * 32], Al[64 * 32], Wh[64 * 32], Wl[64 * 32];
  const int tid = threadIdx.x;
  const int w = tid >> 6, lane = tid & 63;
  const int l15 = lane & 15, quad = lane >> 4;
  const int wn = w >> 1, wm = w & 1;
  const int n0 = blockIdx.y * 64, m0 = blockIdx.x * 64;

  const int row = tid >> 2, cc = tid & 3;
  const int ksw = (cc ^ (row & 3)) * 8;
  const short* gAh = Ah_g + (size_t)(n0 + row) * Dd + ksw;
  const short* gAl = Al_g + (size_t)(n0 + row) * Dd + ksw;
  const short* gWh = Wh_g + (size_t)(m0 + row) * Dd + ksw;
  const short* gWl = Wl_g + (size_t)(m0 + row) * Dd + ksw;
  short* lAh = Ah + tid * 8;
  short* lAl = Al + tid * 8;
  short* lWh = Wh + tid * 8;
  short* lWl = Wl + tid * 8;

  f32x4 acc[2][2];
#pragma unroll
  for (int i = 0; i < 2; ++i)
#pragma unroll
    for (int j = 0; j < 2; ++j) acc[i][j] = f32x4{0.f, 0.f, 0.f, 0.f};

  const int swq = (quad ^ (l15 & 3)) * 8;

  for (int k0 = 0; k0 < Dd; k0 += 32) {
    __syncthreads();
    async_cp16(gAh + k0, lAh);
    async_cp16(gAl + k0, lAl);
    async_cp16(gWh + k0, lWh);
    async_cp16(gWl + k0, lWl);
    __syncthreads();

    bf16x8 ah[2], al[2], wh[2], wl[2];
#pragma unroll
    for (int i = 0; i < 2; ++i) {
      ah[i] = *(const bf16x8*)&Ah[(wn * 32 + i * 16 + l15) * 32 + swq];
      al[i] = *(const bf16x8*)&Al[(wn * 32 + i * 16 + l15) * 32 + swq];
    }
#pragma unroll
    for (int j = 0; j < 2; ++j) {
      wh[j] = *(const bf16x8*)&Wh[(wm * 32 + j * 16 + l15) * 32 + swq];
      wl[j] = *(const bf16x8*)&Wl[(wm * 32 + j * 16 + l15) * 32 + swq];
    }
#pragma unroll
    for (int i = 0; i < 2; ++i)
#pragma unroll
      for (int j = 0; j < 2; ++j) {
        acc[i][j] = __builtin_amdgcn_mfma_f32_16x16x32_bf16(ah[i], wh[j], acc[i][j], 0, 0, 0);
        acc[i][j] = __builtin_amdgcn_mfma_f32_16x16x32_bf16(ah[i], wl[j], acc[i][j], 0, 0, 0);
        acc[i][j] = __builtin_amdgcn_mfma_f32_16x16x32_bf16(al[i], wh[j], acc[i][j], 0, 0, 0);
      }
  }

#pragma unroll
  for (int i = 0; i < 2; ++i)
#pragma unroll
    for (int r = 0; r < 4; ++r) {
      float* crow = C + (size_t)(n0 + wn * 32 + i * 16 + quad * 4 + r) * PH + m0 + wm * 32 + l15;
#pragma unroll
      for (int j = 0; j < 2; ++j) crow[j * 16] = acc[i][j][r];
    }
}

// ---------------- bf16 MFMA GEMM:  C[n,m] = bias[m] + sum_k A[n,k]*W[m,k] ----------
__global__ __launch_bounds__(256) void gemm_bt_bf16(
    const __hip_bfloat16* __restrict__ A, const __hip_bfloat16* __restrict__ W,
    const float* __restrict__ bias, float* __restrict__ C, int K, int M)
{
  __shared__ __align__(16) short As[128 * 32];
  __shared__ __align__(16) short Ws[128 * 32];
  const int tid = threadIdx.x;
  const int w = tid >> 6, lane = tid & 63;
  const int l15 = lane & 15, quad = lane >> 4;
  const int wn = w >> 1, wm = w & 1;
  const int n0 = blockIdx.y * 128, m0 = blockIdx.x * 128;

  const int row = tid >> 2, cc = tid & 3;
  const int ksw = (cc ^ (row & 3)) * 8;
  const short* gA  = (const short*)A + (size_t)(n0 + row) * K + ksw;
  const short* gW  = (const short*)W + (size_t)(m0 + row) * K + ksw;
  short* lA  = As + tid * 8;
  short* lA2 = As + 2048 + tid * 8;
  short* lW  = Ws + tid * 8;
  short* lW2 = Ws + 2048 + tid * 8;

  f32x4 acc[4][4];
#pragma unroll
  for (int i = 0; i < 4; ++i)
#pragma unroll
    for (int j = 0; j < 4; ++j) acc[i][j] = f32x4{0.f, 0.f, 0.f, 0.f};

  const int swq = (quad ^ (l15 & 3)) * 8;

  for (int k0 = 0; k0 < K; k0 += 32) {
    __syncthreads();
    async_cp16(gA + k0, lA);
    async_cp16(gA + 64 * K + k0, lA2);
    async_cp16(gW + k0, lW);
    async_cp16(gW + 64 * K + k0, lW2);
    __syncthreads();

    bf16x8 af[4], bf[4];
#pragma unroll
    for (int i = 0; i < 4; ++i)
      af[i] = *(const bf16x8*)&As[(wn * 64 + i * 16 + l15) * 32 + swq];
#pragma unroll
    for (int j = 0; j < 4; ++j)
      bf[j] = *(const bf16x8*)&Ws[(wm * 64 + j * 16 + l15) * 32 + swq];
#pragma unroll
    for (int i = 0; i < 4; ++i)
#pragma unroll
      for (int j = 0; j < 4; ++j)
        acc[i][j] = __builtin_amdgcn_mfma_f32_16x16x32_bf16(af[i], bf[j], acc[i][j], 0, 0, 0);
  }

  float bv[4];
#pragma unroll
  for (int j = 0; j < 4; ++j) bv[j] = bias[m0 + wm * 64 + j * 16 + l15];
#pragma unroll
  for (int i = 0; i < 4; ++i)
#pragma unroll
    for (int r = 0; r < 4; ++r) {
      float* crow = C + (size_t)(n0 + wn * 64 + i * 16 + quad * 4 + r) * M + m0 + wm * 64 + l15;
#pragma unroll
      for (int j = 0; j < 4; ++j) crow[j * 16] = acc[i][j][r] + bv[j];
    }
}

// ---------------- rotary + cast to bf16 ----------------
__global__ __launch_bounds__(256) void rot_cast_kernel(
    const float* __restrict__ phases, const float* __restrict__ qkv,
    __hip_bfloat16* __restrict__ q_bf, __hip_bfloat16* __restrict__ k_bf)
{
  const int gid = blockIdx.x * 256 + threadIdx.x;   // NT*H*32 = 2M
  const int i = gid & 31;
  const int h = (gid >> 5) & 15;
  const int n = gid >> 9;
  const float ph = phases[n * PH + h * 32 + i];
  float sn, cs;
  __sincosf(ph, &sn, &cs);
  const int base = n * D3 + h * 64 + i;
  const float q1 = qkv[base], q2 = qkv[base + 32];
  const float k1 = qkv[base + Dd], k2 = qkv[base + Dd + 32];
  const float SC = 0.18033688011112042f;   // (1/8) * log2(e): exp2-domain scores
  const int ob = n * Dd + h * 64 + i;
  q_bf[ob]      = __float2bfloat16((q1 * cs - q2 * sn) * SC);
  q_bf[ob + 32] = __float2bfloat16((q1 * sn + q2 * cs) * SC);
  k_bf[ob]      = __float2bfloat16(k1 * cs - k2 * sn);
  k_bf[ob + 32] = __float2bfloat16(k1 * sn + k2 * cs);
}

// ---------------- V transpose + cast: qkv v-part -> vt_g[bh][d=64][tok=2048] bf16 ----
__global__ __launch_bounds__(256) void vtrans_kernel(
    const float* __restrict__ qkv, __hip_bfloat16* __restrict__ vt_g)
{
  __shared__ __align__(16) short Vl[64 * LDK];
  const int tid = threadIdx.x;
  const int tt = blockIdx.x;      // token tile (64 tokens)
  const int bh = blockIdx.y;
  const int b = bh >> 4, h = bh & 15;

  {
    const int tok = tid >> 2, ds = tid & 3;
    const float* src = qkv + (size_t)(b * Ll + tt * 64 + tok) * D3 + 2 * Dd + h * 64 + ds * 16;
    unsigned* dstw = (unsigned*)&Vl[tok * LDK + ds * 16];
#pragma unroll
    for (int jj = 0; jj < 4; ++jj) {
      const float4 f = *(const float4*)(src + jj * 4);
      dstw[jj*2]   = pack2bf(f.x, f.y);
      dstw[jj*2+1] = pack2bf(f.z, f.w);
    }
  }
  __syncthreads();
  {
    const int d = tid >> 2, seg = tid & 3;
    unsigned ow[8];
#pragma unroll
    for (int j = 0; j < 8; ++j) {
      const unsigned short a = (unsigned short)Vl[(seg*16 + 2*j)     * LDK + d];
      const unsigned short c = (unsigned short)Vl[(seg*16 + 2*j + 1) * LDK + d];
      ow[j] = (unsigned)a | ((unsigned)c << 16);
    }
    unsigned* dst = (unsigned*)(vt_g + ((size_t)(bh * 64 + d)) * Ll + tt * 64 + seg * 16);
    *(uint4*)(dst)     = make_uint4(ow[0], ow[1], ow[2], ow[3]);
    *(uint4*)(dst + 4) = make_uint4(ow[4], ow[5], ow[6], ow[7]);
  }
}

// ---------------- bf16 MFMA flash attention, v3 ------------------------------------
// Q-tile 128 (wave owns 32 q = 2 groups), K-tile 64. S^T = K·Q^T via 16x16x32 MFMA.
// No online max (exp2-domain scores bounded; denom reduced once at epilogue).
// PV as O^T = V^T·P at K=16: S^T C-layout registers ARE the P B-operand — no LDS
// round-trip, no cross-lane ops in the kt loop. V^T frags = 2-way-free b64 LDS reads.
__global__ __launch_bounds__(256) void attn_mfma(
    const __hip_bfloat16* __restrict__ q_bf,
    const __hip_bfloat16* __restrict__ k_bf,
    const __hip_bfloat16* __restrict__ vt_g,
    __hip_bfloat16* __restrict__ aout)
{
  __shared__ __align__(16) short Ks[64 * LDK];   // K tile [kt][d]
  __shared__ __align__(16) short Vt[64 * LDK];   // V tile [d][kt]

  const int tid = threadIdx.x;
  const int w = tid >> 6;
  const int lane = tid & 63;
  const int l15 = lane & 15;
  const int quad = lane >> 4;

  const int q0 = blockIdx.x * 128;
  const int bh = blockIdx.y;
  const int b = bh >> 4, h = bh & 15;

  // Q fragments in registers for the whole kernel
  bf16x8 qfrag[2][2];
#pragma unroll
  for (int qg = 0; qg < 2; ++qg)
#pragma unroll
    for (int kh = 0; kh < 2; ++kh) {
      const size_t qrow = (size_t)(b * Ll + q0 + w * 32 + qg * 16 + l15);
      qfrag[qg][kh] = *(const bf16x8*)(q_bf + qrow * Dd + h * 64 + kh * 32 + quad * 8);
    }

  // O^T accumulators: acc[dt][qg][r] = O[q = qg*16+l15][d = dt*16 + quad*4 + r]
  f32x4 acc[4][2];
#pragma unroll
  for (int dt = 0; dt < 4; ++dt)
#pragma unroll
    for (int qg = 0; qg < 2; ++qg) acc[dt][qg] = f32x4{0.f, 0.f, 0.f, 0.f};
  float l_acc[2] = {0.f, 0.f};

  const int srow = tid >> 2, sseg = tid & 3;
  const __hip_bfloat16* kbase = k_bf + (size_t)(b * Ll + srow) * Dd + h * 64 + sseg * 16;
  const __hip_bfloat16* vbase = vt_g + ((size_t)(bh * 64 + srow)) * Ll + sseg * 16;

  for (int kt = 0; kt < Ll / 64; ++kt) {
    __syncthreads();
    {
      const uint4* kg = (const uint4*)(kbase + (size_t)kt * 64 * Dd);
      *(uint4*)&Ks[srow * LDK + sseg * 16]     = kg[0];
      *(uint4*)&Ks[srow * LDK + sseg * 16 + 8] = kg[1];
      const uint4* vg = (const uint4*)(vbase + kt * 64);
      *(uint4*)&Vt[srow * LDK + sseg * 16]     = vg[0];
      *(uint4*)&Vt[srow * LDK + sseg * 16 + 8] = vg[1];
    }
    __syncthreads();

    // S^T strips: s[n][qg] rows kt = n*16+quad*4+r, col q = qg*16+l15
    f32x4 s[4][2];
#pragma unroll
    for (int n = 0; n < 4; ++n)
#pragma unroll
      for (int qg = 0; qg < 2; ++qg) s[n][qg] = f32x4{0.f, 0.f, 0.f, 0.f};
#pragma unroll
    for (int n = 0; n < 4; ++n)
#pragma unroll
      for (int kh = 0; kh < 2; ++kh) {
        const bf16x8 af = *(const bf16x8*)&Ks[(n * 16 + l15) * LDK + kh * 32 + quad * 8];
        s[n][0] = __builtin_amdgcn_mfma_f32_16x16x32_bf16(af, qfrag[0][kh], s[n][0], 0, 0, 0);
        s[n][1] = __builtin_amdgcn_mfma_f32_16x16x32_bf16(af, qfrag[1][kh], s[n][1], 0, 0, 0);
      }

    // exp2 (no max subtraction), in-lane denominator accumulate, pack P B-frags
    uint2 bq[4][2];
#pragma unroll
    for (int qg = 0; qg < 2; ++qg)
#pragma unroll
      for (int n = 0; n < 4; ++n) {
        const float p0 = __builtin_amdgcn_exp2f(s[n][qg][0]);
        const float p1 = __builtin_amdgcn_exp2f(s[n][qg][1]);
        const float p2 = __builtin_amdgcn_exp2f(s[n][qg][2]);
        const float p3 = __builtin_amdgcn_exp2f(s[n][qg][3]);
        l_acc[qg] += (p0 + p1) + (p2 + p3);
        bq[n][qg] = make_uint2(pack2bf(p0, p1), pack2bf(p2, p3));
      }

    // O^T += V^T · P   (K=16 per n-strip; frag registers, no LDS round-trip)
#pragma unroll
    for (int n = 0; n < 4; ++n) {
      const bf16x4 pb0 = u2bf4(bq[n][0]);
      const bf16x4 pb1 = u2bf4(bq[n][1]);
#pragma unroll
      for (int dt = 0; dt < 4; ++dt) {
        const bf16x4 va = *(const bf16x4*)&Vt[(dt * 16 + l15) * LDK + n * 16 + quad * 4];
        acc[dt][0] = pv_mfma(va, pb0, acc[dt][0]);
        acc[dt][1] = pv_mfma(va, pb1, acc[dt][1]);
      }
    }
  }

  // epilogue: reduce denominator across quads (once), normalize, store bf16
#pragma unroll
  for (int qg = 0; qg < 2; ++qg) {
    float l = l_acc[qg];
    l += __shfl_xor(l, 16);
    l += __shfl_xor(l, 32);
    const float linv = 1.f / l;
    const size_t q = (size_t)(b * Ll + q0 + w * 32 + qg * 16 + l15);
#pragma unroll
    for (int dt = 0; dt < 4; ++dt) {
      const uint2 o = make_uint2(
          pack2bf(acc[dt][qg][0] * linv, acc[dt][qg][1] * linv),
          pack2bf(acc[dt][qg][2] * linv, acc[dt][qg][3] * linv));
      *(uint2*)&aout[q * Dd + h * 64 + dt * 16 + quad * 4] = o;
    }
  }
}

extern "C" void kernel_launch(void* const* d_in, const int* in_sizes, int n_in,
                              void* d_out, int out_size, void* d_ws, size_t ws_size,
                              hipStream_t stream) {
  const float* x     = (const float*)d_in[0];
  const float* p     = (const float*)d_in[1];
  const float* W_qkv = (const float*)d_in[2];
  const float* b_qkv = (const float*)d_in[3];
  const float* W_out = (const float*)d_in[4];
  const float* b_out = (const float*)d_in[5];
  const float* proj  = (const float*)d_in[6];
  float* out = (float*)d_out;

  // workspace overlay (72 MiB, proven footprint). Stream order makes reuse safe:
  //  [0,8Mi):   phases fp32 (dead after rot_cast)      -> vt_g bf16
  //  [8,56Mi):  PHASE A: p_hi [8,16), p_lo [16,24), projt_hi [24,25), projt_lo [25,26)
  //             PHASE B (after phases GEMM): qkv fp32
  //             PHASE C (after vtrans): aout_bf [8,16), wout_bf [16,18)
  //  [56,64Mi): x_bf (dead after qkv GEMM)             -> q_bf
  //  [64,72Mi): wqkv_bf (dead after qkv GEMM)          -> k_bf
  char* wsb = (char*)d_ws;
  float*          phases   = (float*)(wsb);
  __hip_bfloat16* vt_g     = (__hip_bfloat16*)(wsb);
  short*          p_hi     = (short*)(wsb + (8u << 20));
  short*          p_lo     = (short*)(wsb + (16u << 20));
  short*          projt_hi = (short*)(wsb + (24u << 20));
  short*          projt_lo = (short*)(wsb + (25u << 20));
  float*          qkv      = (float*)(wsb + (8u << 20));
  __hip_bfloat16* aout_bf  = (__hip_bfloat16*)(wsb + (8u << 20));
  __hip_bfloat16* wout_bf  = (__hip_bfloat16*)(wsb + (16u << 20));
  __hip_bfloat16* x_bf     = (__hip_bfloat16*)(wsb + (56u << 20));
  __hip_bfloat16* q_bf     = (__hip_bfloat16*)(wsb + (56u << 20));
  __hip_bfloat16* wqkv_bf  = (__hip_bfloat16*)(wsb + (64u << 20));
  __hip_bfloat16* k_bf     = (__hip_bfloat16*)(wsb + (64u << 20));

  // phases pipeline (split-bf16, fp32-grade accuracy at MFMA rate)
  split_cast_kernel<<<4096, 256, 0, stream>>>((const float4*)p, (uint2*)p_hi, (uint2*)p_lo, 1048576);
  trans_split_kernel<<<dim3(Dd / 64, PH / 64), 256, 0, stream>>>(proj, projt_hi, projt_lo);
  gemm_nn_split<<<dim3(PH / 64, NT / 64), 256, 0, stream>>>(p_hi, p_lo, projt_hi, projt_lo, phases);
  // qkv pipeline
  cast4_kernel<<<4096, 256, 0, stream>>>((const float4*)x, (uint2*)x_bf, 1048576);
  cast4_kernel<<<3072, 256, 0, stream>>>((const float4*)W_qkv, (uint2*)wqkv_bf, 786432);
  gemm_bt_bf16<<<dim3(D3 / 128, NT / 128), 256, 0, stream>>>(x_bf, wqkv_bf, b_qkv, qkv, Dd, D3);
  // rotate q,k -> bf16 (reads phases + fp32 qkv)
  rot_cast_kernel<<<dim3((NT * Hh * 32) / 256), 256, 0, stream>>>(phases, qkv, q_bf, k_bf);
  // v -> transposed bf16 (overwrites phases region)
  vtrans_kernel<<<dim3(Ll / 64, Bb * Hh), 256, 0, stream>>>(qkv, vt_g);
  // W_out cast (into dead qkv region)
  cast4_kernel<<<1024, 256, 0, stream>>>((const float4*)W_out, (uint2*)wout_bf, 262144);
  // flash attention -> aout bf16 (Q-tile 128, 512 blocks)
  attn_mfma<<<dim3(Ll / 128, Bb * Hh), 256, 0, stream>>>(q_bf, k_bf, vt_g, aout_bf);
  // out = aout @ W_out^T + b_out
  gemm_bt_bf16<<<dim3(Dd / 128, NT / 128), 256, 0, stream>>>(aout_bf, wout_bf, b_out, out, Dd, Dd);
}

// Round 6
// 275.050 us; speedup vs baseline: 4.3287x; 1.0345x over previous
//
#include <hip/hip_runtime.h>
#include <hip/hip_bf16.h>
#include <math.h>

namespace {
constexpr int Bb = 2;
constexpr int Ll = 2048;
constexpr int Dd = 1024;
constexpr int Hh = 16;
constexpr int NT = Bb * Ll;   // 4096 tokens
constexpr int D3 = 3 * Dd;    // 3072
constexpr int PH = Dd / 2;    // 512 phases per token
constexpr int LDK = 72;       // LDS row stride (bf16) for attn tiles
}

typedef __attribute__((ext_vector_type(8))) short bf16x8;
typedef __attribute__((ext_vector_type(4))) short bf16x4;
typedef __attribute__((ext_vector_type(4))) float f32x4;

#if defined(__has_builtin)
#if __has_builtin(__builtin_amdgcn_mfma_f32_16x16x16bf16_1k)
#define HAVE_MFMA16 1
#endif
#endif

__device__ inline unsigned pack2bf(float a, float b) {
  __hip_bfloat162 t = __float22bfloat162_rn(float2{a, b});
  union { __hip_bfloat162 h; unsigned u; } cv; cv.h = t;
  return cv.u;
}

__device__ inline bf16x4 u2bf4(uint2 u) {
  union { uint2 u; bf16x4 v; } c; c.u = u; return c.v;
}

// PV matmul piece: D = V^T-frag (A) x P-frag (B) + C at K=16 granularity.
__device__ inline f32x4 pv_mfma(bf16x4 va, bf16x4 vb, f32x4 c) {
#ifdef HAVE_MFMA16
  return __builtin_amdgcn_mfma_f32_16x16x16bf16_1k(va, vb, c, 0, 0, 0);
#else
  const bf16x8 a8 = {va[0], va[1], va[2], va[3], 0, 0, 0, 0};
  const bf16x8 b8 = {vb[0], vb[1], vb[2], vb[3], 0, 0, 0, 0};
  return __builtin_amdgcn_mfma_f32_16x16x32_bf16(a8, b8, c, 0, 0, 0);
#endif
}

__device__ inline void async_cp16(const void* gsrc, void* ldst) {
  __builtin_amdgcn_global_load_lds(
      (const __attribute__((address_space(1))) unsigned int*)gsrc,
      (__attribute__((address_space(3))) unsigned int*)ldst, 16, 0, 0);
}

// ---------------- merged fp32 -> bf16 casts: x, W_qkv, W_out ----------------
__global__ __launch_bounds__(256) void cast3_kernel(
    const float4* __restrict__ x, const float4* __restrict__ wq,
    const float4* __restrict__ wo,
    uint2* __restrict__ xd, uint2* __restrict__ wqd, uint2* __restrict__ wod)
{
  int i = blockIdx.x * 256 + threadIdx.x;   // grid covers exactly 2,097,152
  const float4* s; uint2* d;
  if (i < 1048576) { s = x; d = xd; }
  else if (i < 1048576 + 786432) { i -= 1048576; s = wq; d = wqd; }
  else { i -= 1048576 + 786432; s = wo; d = wod; }
  const float4 f = s[i];
  d[i] = make_uint2(pack2bf(f.x, f.y), pack2bf(f.z, f.w));
}

// ---------------- fp32 -> hi/lo bf16 split cast ----------------
__global__ __launch_bounds__(256) void split_cast_kernel(
    const float4* __restrict__ src, uint2* __restrict__ hi, uint2* __restrict__ lo, int n4)
{
  const int i = blockIdx.x * 256 + threadIdx.x;
  if (i >= n4) return;
  const float4 f = src[i];
  float hf[4], lf[4];
  const float ff[4] = {f.x, f.y, f.z, f.w};
#pragma unroll
  for (int j = 0; j < 4; ++j) {
    const __hip_bfloat16 h = __float2bfloat16(ff[j]);
    hf[j] = __bfloat162float(h);
    lf[j] = ff[j] - hf[j];
  }
  hi[i] = make_uint2(pack2bf(hf[0], hf[1]), pack2bf(hf[2], hf[3]));
  lo[i] = make_uint2(pack2bf(lf[0], lf[1]), pack2bf(lf[2], lf[3]));
}

// ---------------- proj transpose + hi/lo split: [1024 d][512 m] -> [512 m][1024 d] ---
__global__ __launch_bounds__(256) void trans_split_kernel(
    const float* __restrict__ proj, short* __restrict__ th, short* __restrict__ tl)
{
  __shared__ float Ls[64][65];
  const int tid = threadIdx.x;
  const int d0 = blockIdx.x * 64, m0 = blockIdx.y * 64;
  const int r = tid >> 4, c4 = (tid & 15) * 4;
#pragma unroll
  for (int it = 0; it < 4; ++it) {
    const int row = it * 16 + r;
    const float4 v = *(const float4*)&proj[(size_t)(d0 + row) * PH + m0 + c4];
    Ls[row][c4] = v.x; Ls[row][c4+1] = v.y; Ls[row][c4+2] = v.z; Ls[row][c4+3] = v.w;
  }
  __syncthreads();
#pragma unroll
  for (int it = 0; it < 4; ++it) {
    const int row = it * 16 + r;
    float hf[4], lf[4];
#pragma unroll
    for (int j = 0; j < 4; ++j) {
      const float v = Ls[c4 + j][row];
      const __hip_bfloat16 h = __float2bfloat16(v);
      hf[j] = __bfloat162float(h);
      lf[j] = v - hf[j];
    }
    *(uint2*)&th[(size_t)(m0 + row) * Dd + d0 + c4] = make_uint2(pack2bf(hf[0], hf[1]), pack2bf(hf[2], hf[3]));
    *(uint2*)&tl[(size_t)(m0 + row) * Dd + d0 + c4] = make_uint2(pack2bf(lf[0], lf[1]), pack2bf(lf[2], lf[3]));
  }
}

// ---------------- split-bf16 MFMA GEMM for phases --------------------------------
__global__ __launch_bounds__(256) void gemm_nn_split(
    const short* __restrict__ Ah_g, const short* __restrict__ Al_g,
    const short* __restrict__ Wh_g, const short* __restrict__ Wl_g,
    float* __restrict__ C)
{
  __shared__ __align__(16) short Ah[64 * 32], Al[64 * 32], Wh[64 * 32], Wl[64 * 32];
  const int tid = threadIdx.x;
  const int w = tid >> 6, lane = tid & 63;
  const int l15 = lane & 15, quad = lane >> 4;
  const int wn = w >> 1, wm = w & 1;
  const int n0 = blockIdx.y * 64, m0 = blockIdx.x * 64;

  const int row = tid >> 2, cc = tid & 3;
  const int ksw = (cc ^ (row & 3)) * 8;
  const short* gAh = Ah_g + (size_t)(n0 + row) * Dd + ksw;
  const short* gAl = Al_g + (size_t)(n0 + row) * Dd + ksw;
  const short* gWh = Wh_g + (size_t)(m0 + row) * Dd + ksw;
  const short* gWl = Wl_g + (size_t)(m0 + row) * Dd + ksw;
  short* lAh = Ah + tid * 8;
  short* lAl = Al + tid * 8;
  short* lWh = Wh + tid * 8;
  short* lWl = Wl + tid * 8;

  f32x4 acc[2][2];
#pragma unroll
  for (int i = 0; i < 2; ++i)
#pragma unroll
    for (int j = 0; j < 2; ++j) acc[i][j] = f32x4{0.f, 0.f, 0.f, 0.f};

  const int swq = (quad ^ (l15 & 3)) * 8;

  for (int k0 = 0; k0 < Dd; k0 += 32) {
    __syncthreads();
    async_cp16(gAh + k0, lAh);
    async_cp16(gAl + k0, lAl);
    async_cp16(gWh + k0, lWh);
    async_cp16(gWl + k0, lWl);
    __syncthreads();

    bf16x8 ah[2], al[2], wh[2], wl[2];
#pragma unroll
    for (int i = 0; i < 2; ++i) {
      ah[i] = *(const bf16x8*)&Ah[(wn * 32 + i * 16 + l15) * 32 + swq];
      al[i] = *(const bf16x8*)&Al[(wn * 32 + i * 16 + l15) * 32 + swq];
    }
#pragma unroll
    for (int j = 0; j < 2; ++j) {
      wh[j] = *(const bf16x8*)&Wh[(wm * 32 + j * 16 + l15) * 32 + swq];
      wl[j] = *(const bf16x8*)&Wl[(wm * 32 + j * 16 + l15) * 32 + swq];
    }
#pragma unroll
    for (int i = 0; i < 2; ++i)
#pragma unroll
      for (int j = 0; j < 2; ++j) {
        acc[i][j] = __builtin_amdgcn_mfma_f32_16x16x32_bf16(ah[i], wh[j], acc[i][j], 0, 0, 0);
        acc[i][j] = __builtin_amdgcn_mfma_f32_16x16x32_bf16(ah[i], wl[j], acc[i][j], 0, 0, 0);
        acc[i][j] = __builtin_amdgcn_mfma_f32_16x16x32_bf16(al[i], wh[j], acc[i][j], 0, 0, 0);
      }
  }

#pragma unroll
  for (int i = 0; i < 2; ++i)
#pragma unroll
    for (int r = 0; r < 4; ++r) {
      float* crow = C + (size_t)(n0 + wn * 32 + i * 16 + quad * 4 + r) * PH + m0 + wm * 32 + l15;
#pragma unroll
      for (int j = 0; j < 2; ++j) crow[j * 16] = acc[i][j][r];
    }
}

// ---------------- qkv GEMM with FUSED rotary/cast/V-transpose epilogue --------------
// C = x @ W_qkv^T + b_qkv computed in MFMA; epilogue branches by m-region:
//   m<1024  -> rotate (phases) + scale log2e/8 -> q_bf[tok][1024]
//   <2048   -> rotate -> k_bf[tok][1024]
//   else    -> vt_g[bh][d=64][tok=2048] (transposed, 8B stores along 4 acc rows)
// Rotation pairs (i, i+32) are cols (j, j+2) of the fragment grid: same lane.
__global__ __launch_bounds__(256) void gemm_qkv_fused(
    const __hip_bfloat16* __restrict__ A, const __hip_bfloat16* __restrict__ W,
    const float* __restrict__ bias, const float* __restrict__ phases,
    __hip_bfloat16* __restrict__ q_bf, __hip_bfloat16* __restrict__ k_bf,
    __hip_bfloat16* __restrict__ vt_g)
{
  __shared__ __align__(16) short As[128 * 32];
  __shared__ __align__(16) short Ws[128 * 32];
  const int tid = threadIdx.x;
  const int w = tid >> 6, lane = tid & 63;
  const int l15 = lane & 15, quad = lane >> 4;
  const int wn = w >> 1, wm = w & 1;
  const int n0 = blockIdx.y * 128, m0 = blockIdx.x * 128;

  const int row = tid >> 2, cc = tid & 3;
  const int ksw = (cc ^ (row & 3)) * 8;
  const short* gA  = (const short*)A + (size_t)(n0 + row) * Dd + ksw;
  const short* gW  = (const short*)W + (size_t)(m0 + row) * Dd + ksw;
  short* lA  = As + tid * 8;
  short* lA2 = As + 2048 + tid * 8;
  short* lW  = Ws + tid * 8;
  short* lW2 = Ws + 2048 + tid * 8;

  f32x4 acc[4][4];
#pragma unroll
  for (int i = 0; i < 4; ++i)
#pragma unroll
    for (int j = 0; j < 4; ++j) acc[i][j] = f32x4{0.f, 0.f, 0.f, 0.f};

  const int swq = (quad ^ (l15 & 3)) * 8;

  for (int k0 = 0; k0 < Dd; k0 += 32) {
    __syncthreads();
    async_cp16(gA + k0, lA);
    async_cp16(gA + 64 * Dd + k0, lA2);
    async_cp16(gW + k0, lW);
    async_cp16(gW + 64 * Dd + k0, lW2);
    __syncthreads();

    bf16x8 af[4], bf[4];
#pragma unroll
    for (int i = 0; i < 4; ++i)
      af[i] = *(const bf16x8*)&As[(wn * 64 + i * 16 + l15) * 32 + swq];
#pragma unroll
    for (int j = 0; j < 4; ++j)
      bf[j] = *(const bf16x8*)&Ws[(wm * 64 + j * 16 + l15) * 32 + swq];
#pragma unroll
    for (int i = 0; i < 4; ++i)
#pragma unroll
      for (int j = 0; j < 4; ++j)
        acc[i][j] = __builtin_amdgcn_mfma_f32_16x16x32_bf16(af[i], bf[j], acc[i][j], 0, 0, 0);
  }

  float bv[4];
#pragma unroll
  for (int j = 0; j < 4; ++j) bv[j] = bias[m0 + wm * 64 + j * 16 + l15];

  const int region = m0 >> 10;                 // 0=q, 1=k, 2=v (128 | 1024, block-uniform)
  const int mloc = (m0 & 1023) + wm * 64;      // within-region col base (one head per wm)
  const int h = mloc >> 6;

  if (region < 2) {
    __hip_bfloat16* dst = region == 0 ? q_bf : k_bf;
    const float SC = region == 0 ? 0.18033688011112042f : 1.0f;  // (1/8)*log2(e) on q
#pragma unroll
    for (int i = 0; i < 4; ++i)
#pragma unroll
      for (int r = 0; r < 4; ++r) {
        const int n = n0 + wn * 64 + i * 16 + quad * 4 + r;
        const float* phrow = phases + (size_t)n * PH + h * 32;
        __hip_bfloat16* drow = dst + (size_t)n * Dd + h * 64;
#pragma unroll
        for (int pz = 0; pz < 2; ++pz) {
          const float ph = phrow[pz * 16 + l15];
          float sn, cs;
          __sincosf(ph, &sn, &cs);
          const float a1 = acc[i][pz][r] + bv[pz];
          const float a2 = acc[i][pz + 2][r] + bv[pz + 2];
          drow[pz * 16 + l15]      = __float2bfloat16((a1 * cs - a2 * sn) * SC);
          drow[pz * 16 + 32 + l15] = __float2bfloat16((a1 * sn + a2 * cs) * SC);
        }
      }
  } else {
    const int bh = (n0 >> 11) * 16 + h;
    const int tokb = (n0 & 2047) + wn * 64;
#pragma unroll
    for (int i = 0; i < 4; ++i)
#pragma unroll
      for (int j = 0; j < 4; ++j) {
        const uint2 o = make_uint2(
            pack2bf(acc[i][j][0] + bv[j], acc[i][j][1] + bv[j]),
            pack2bf(acc[i][j][2] + bv[j], acc[i][j][3] + bv[j]));
        const int d = j * 16 + l15;
        *(uint2*)&vt_g[(size_t)(bh * 64 + d) * Ll + tokb + i * 16 + quad * 4] = o;
      }
  }
}

// ---------------- bf16 MFMA GEMM (out-proj):  C = bias + A @ W^T, fp32 out ----------
__global__ __launch_bounds__(256) void gemm_bt_bf16(
    const __hip_bfloat16* __restrict__ A, const __hip_bfloat16* __restrict__ W,
    const float* __restrict__ bias, float* __restrict__ C, int K, int M)
{
  __shared__ __align__(16) short As[128 * 32];
  __shared__ __align__(16) short Ws[128 * 32];
  const int tid = threadIdx.x;
  const int w = tid >> 6, lane = tid & 63;
  const int l15 = lane & 15, quad = lane >> 4;
  const int wn = w >> 1, wm = w & 1;
  const int n0 = blockIdx.y * 128, m0 = blockIdx.x * 128;

  const int row = tid >> 2, cc = tid & 3;
  const int ksw = (cc ^ (row & 3)) * 8;
  const short* gA  = (const short*)A + (size_t)(n0 + row) * K + ksw;
  const short* gW  = (const short*)W + (size_t)(m0 + row) * K + ksw;
  short* lA  = As + tid * 8;
  short* lA2 = As + 2048 + tid * 8;
  short* lW  = Ws + tid * 8;
  short* lW2 = Ws + 2048 + tid * 8;

  f32x4 acc[4][4];
#pragma unroll
  for (int i = 0; i < 4; ++i)
#pragma unroll
    for (int j = 0; j < 4; ++j) acc[i][j] = f32x4{0.f, 0.f, 0.f, 0.f};

  const int swq = (quad ^ (l15 & 3)) * 8;

  for (int k0 = 0; k0 < K; k0 += 32) {
    __syncthreads();
    async_cp16(gA + k0, lA);
    async_cp16(gA + 64 * K + k0, lA2);
    async_cp16(gW + k0, lW);
    async_cp16(gW + 64 * K + k0, lW2);
    __syncthreads();

    bf16x8 af[4], bf[4];
#pragma unroll
    for (int i = 0; i < 4; ++i)
      af[i] = *(const bf16x8*)&As[(wn * 64 + i * 16 + l15) * 32 + swq];
#pragma unroll
    for (int j = 0; j < 4; ++j)
      bf[j] = *(const bf16x8*)&Ws[(wm * 64 + j * 16 + l15) * 32 + swq];
#pragma unroll
    for (int i = 0; i < 4; ++i)
#pragma unroll
      for (int j = 0; j < 4; ++j)
        acc[i][j] = __builtin_amdgcn_mfma_f32_16x16x32_bf16(af[i], bf[j], acc[i][j], 0, 0, 0);
  }

  float bv[4];
#pragma unroll
  for (int j = 0; j < 4; ++j) bv[j] = bias[m0 + wm * 64 + j * 16 + l15];
#pragma unroll
  for (int i = 0; i < 4; ++i)
#pragma unroll
    for (int r = 0; r < 4; ++r) {
      float* crow = C + (size_t)(n0 + wn * 64 + i * 16 + quad * 4 + r) * M + m0 + wm * 64 + l15;
#pragma unroll
      for (int j = 0; j < 4; ++j) crow[j * 16] = acc[i][j][r] + bv[j];
    }
}

// ---------------- bf16 MFMA flash attention (register PV, trunc-pack) ---------------
// Q-tile 128 (wave owns 32 q), K-tile 64. S^T = K·Q^T. exp2 domain, no online max.
// P packed by TRUNCATION (v_perm_b32); denominator sums the SAME truncated values
// (ratio-consistent -> unbiased). PV: O^T = V^T·P at K=16, frags direct from regs.
__global__ __launch_bounds__(256) void attn_mfma(
    const __hip_bfloat16* __restrict__ q_bf,
    const __hip_bfloat16* __restrict__ k_bf,
    const __hip_bfloat16* __restrict__ vt_g,
    __hip_bfloat16* __restrict__ aout)
{
  __shared__ __align__(16) short Ks[64 * LDK];
  __shared__ __align__(16) short Vt[64 * LDK];

  const int tid = threadIdx.x;
  const int w = tid >> 6;
  const int lane = tid & 63;
  const int l15 = lane & 15;
  const int quad = lane >> 4;

  const int q0 = blockIdx.x * 128;
  const int bh = blockIdx.y;
  const int b = bh >> 4, h = bh & 15;

  bf16x8 qfrag[2][2];
#pragma unroll
  for (int qg = 0; qg < 2; ++qg)
#pragma unroll
    for (int kh = 0; kh < 2; ++kh) {
      const size_t qrow = (size_t)(b * Ll + q0 + w * 32 + qg * 16 + l15);
      qfrag[qg][kh] = *(const bf16x8*)(q_bf + qrow * Dd + h * 64 + kh * 32 + quad * 8);
    }

  f32x4 acc[4][2];
#pragma unroll
  for (int dt = 0; dt < 4; ++dt)
#pragma unroll
    for (int qg = 0; qg < 2; ++qg) acc[dt][qg] = f32x4{0.f, 0.f, 0.f, 0.f};
  float l_acc[2] = {0.f, 0.f};

  const int srow = tid >> 2, sseg = tid & 3;
  const __hip_bfloat16* kbase = k_bf + (size_t)(b * Ll + srow) * Dd + h * 64 + sseg * 16;
  const __hip_bfloat16* vbase = vt_g + ((size_t)(bh * 64 + srow)) * Ll + sseg * 16;

  for (int kt = 0; kt < Ll / 64; ++kt) {
    __syncthreads();
    {
      const uint4* kg = (const uint4*)(kbase + (size_t)kt * 64 * Dd);
      *(uint4*)&Ks[srow * LDK + sseg * 16]     = kg[0];
      *(uint4*)&Ks[srow * LDK + sseg * 16 + 8] = kg[1];
      const uint4* vg = (const uint4*)(vbase + kt * 64);
      *(uint4*)&Vt[srow * LDK + sseg * 16]     = vg[0];
      *(uint4*)&Vt[srow * LDK + sseg * 16 + 8] = vg[1];
    }
    __syncthreads();

    f32x4 s[4][2];
#pragma unroll
    for (int n = 0; n < 4; ++n)
#pragma unroll
      for (int qg = 0; qg < 2; ++qg) s[n][qg] = f32x4{0.f, 0.f, 0.f, 0.f};
#pragma unroll
    for (int n = 0; n < 4; ++n)
#pragma unroll
      for (int kh = 0; kh < 2; ++kh) {
        const bf16x8 af = *(const bf16x8*)&Ks[(n * 16 + l15) * LDK + kh * 32 + quad * 8];
        s[n][0] = __builtin_amdgcn_mfma_f32_16x16x32_bf16(af, qfrag[0][kh], s[n][0], 0, 0, 0);
        s[n][1] = __builtin_amdgcn_mfma_f32_16x16x32_bf16(af, qfrag[1][kh], s[n][1], 0, 0, 0);
      }

    // exp2 + truncation-pack (1 v_perm per pair); denominator sums truncated values
    uint2 bq[4][2];
#pragma unroll
    for (int qg = 0; qg < 2; ++qg)
#pragma unroll
      for (int n = 0; n < 4; ++n) {
        union { float f; unsigned u; } p0, p1, p2, p3, t0, t1, t2, t3;
        p0.f = __builtin_amdgcn_exp2f(s[n][qg][0]);
        p1.f = __builtin_amdgcn_exp2f(s[n][qg][1]);
        p2.f = __builtin_amdgcn_exp2f(s[n][qg][2]);
        p3.f = __builtin_amdgcn_exp2f(s[n][qg][3]);
        const unsigned lo = __builtin_amdgcn_perm(p1.u, p0.u, 0x07060302u);
        const unsigned hi = __builtin_amdgcn_perm(p3.u, p2.u, 0x07060302u);
        bq[n][qg] = make_uint2(lo, hi);
        t0.u = lo << 16; t1.u = lo & 0xffff0000u;
        t2.u = hi << 16; t3.u = hi & 0xffff0000u;
        l_acc[qg] += (t0.f + t1.f) + (t2.f + t3.f);
      }

    // O^T += V^T · P  (K=16 per strip, frag registers)
#pragma unroll
    for (int n = 0; n < 4; ++n) {
      const bf16x4 pb0 = u2bf4(bq[n][0]);
      const bf16x4 pb1 = u2bf4(bq[n][1]);
#pragma unroll
      for (int dt = 0; dt < 4; ++dt) {
        const bf16x4 va = *(const bf16x4*)&Vt[(dt * 16 + l15) * LDK + n * 16 + quad * 4];
        acc[dt][0] = pv_mfma(va, pb0, acc[dt][0]);
        acc[dt][1] = pv_mfma(va, pb1, acc[dt][1]);
      }
    }
  }

#pragma unroll
  for (int qg = 0; qg < 2; ++qg) {
    float l = l_acc[qg];
    l += __shfl_xor(l, 16);
    l += __shfl_xor(l, 32);
    const float linv = 1.f / l;
    const size_t q = (size_t)(b * Ll + q0 + w * 32 + qg * 16 + l15);
#pragma unroll
    for (int dt = 0; dt < 4; ++dt) {
      const uint2 o = make_uint2(
          pack2bf(acc[dt][qg][0] * linv, acc[dt][qg][1] * linv),
          pack2bf(acc[dt][qg][2] * linv, acc[dt][qg][3] * linv));
      *(uint2*)&aout[q * Dd + h * 64 + dt * 16 + quad * 4] = o;
    }
  }
}

extern "C" void kernel_launch(void* const* d_in, const int* in_sizes, int n_in,
                              void* d_out, int out_size, void* d_ws, size_t ws_size,
                              hipStream_t stream) {
  const float* x     = (const float*)d_in[0];
  const float* p     = (const float*)d_in[1];
  const float* W_qkv = (const float*)d_in[2];
  const float* b_qkv = (const float*)d_in[3];
  const float* W_out = (const float*)d_in[4];
  const float* b_out = (const float*)d_in[5];
  const float* proj  = (const float*)d_in[6];
  float* out = (float*)d_out;

  // workspace overlay (58 MiB used, < proven 72 MiB footprint):
  //  [0,8Mi):   phases fp32 (read by fused qkv epilogue)
  //  [8,16Mi):  p_hi  -> (dead after phases gemm) aout_bf
  //  [16,24Mi): p_lo  -> (dead after phases gemm) vt_g
  //  [24,25Mi): projt_hi   [25,26Mi): projt_lo
  //  [26,34Mi): q_bf   [34,42Mi): k_bf
  //  [42,50Mi): x_bf   [50,56Mi): wqkv_bf   [56,58Mi): wout_bf
  char* wsb = (char*)d_ws;
  float*          phases   = (float*)(wsb);
  short*          p_hi     = (short*)(wsb + (8u << 20));
  __hip_bfloat16* aout_bf  = (__hip_bfloat16*)(wsb + (8u << 20));
  short*          p_lo     = (short*)(wsb + (16u << 20));
  __hip_bfloat16* vt_g     = (__hip_bfloat16*)(wsb + (16u << 20));
  short*          projt_hi = (short*)(wsb + (24u << 20));
  short*          projt_lo = (short*)(wsb + (25u << 20));
  __hip_bfloat16* q_bf     = (__hip_bfloat16*)(wsb + (26u << 20));
  __hip_bfloat16* k_bf     = (__hip_bfloat16*)(wsb + (34u << 20));
  __hip_bfloat16* x_bf     = (__hip_bfloat16*)(wsb + (42u << 20));
  __hip_bfloat16* wqkv_bf  = (__hip_bfloat16*)(wsb + (50u << 20));
  __hip_bfloat16* wout_bf  = (__hip_bfloat16*)(wsb + (56u << 20));

  // input prep
  split_cast_kernel<<<4096, 256, 0, stream>>>((const float4*)p, (uint2*)p_hi, (uint2*)p_lo, 1048576);
  trans_split_kernel<<<dim3(Dd / 64, PH / 64), 256, 0, stream>>>(proj, projt_hi, projt_lo);
  cast3_kernel<<<8192, 256, 0, stream>>>((const float4*)x, (const float4*)W_qkv, (const float4*)W_out,
                                         (uint2*)x_bf, (uint2*)wqkv_bf, (uint2*)wout_bf);
  // phases = p @ proj (split-bf16, fp32-grade accuracy)
  gemm_nn_split<<<dim3(PH / 64, NT / 64), 256, 0, stream>>>(p_hi, p_lo, projt_hi, projt_lo, phases);
  // qkv GEMM + fused rotary/cast/V-transpose epilogue
  gemm_qkv_fused<<<dim3(D3 / 128, NT / 128), 256, 0, stream>>>(x_bf, wqkv_bf, b_qkv, phases,
                                                               q_bf, k_bf, vt_g);
  // flash attention -> aout bf16
  attn_mfma<<<dim3(Ll / 128, Bb * Hh), 256, 0, stream>>>(q_bf, k_bf, vt_g, aout_bf);
  // out = aout @ W_out^T + b_out
  gemm_bt_bf16<<<dim3(Dd / 128, NT / 128), 256, 0, stream>>>(aout_bf, wout_bf, b_out, out, Dd, Dd);
}

// Round 7
// 269.317 us; speedup vs baseline: 4.4208x; 1.0213x over previous
//
#include <hip/hip_runtime.h>
#include <hip/hip_bf16.h>
#include <math.h>

namespace {
constexpr int Bb = 2;
constexpr int Ll = 2048;
constexpr int Dd = 1024;
constexpr int Hh = 16;
constexpr int NT = Bb * Ll;   // 4096 tokens
constexpr int D3 = 3 * Dd;    // 3072
constexpr int PH = Dd / 2;    // 512 phases per token
constexpr int LDK = 72;       // LDS row stride (bf16) for attn tiles
}

typedef __attribute__((ext_vector_type(8))) short bf16x8;
typedef __attribute__((ext_vector_type(4))) short bf16x4;
typedef __attribute__((ext_vector_type(4))) float f32x4;

#if defined(__has_builtin)
#if __has_builtin(__builtin_amdgcn_mfma_f32_16x16x16bf16_1k)
#define HAVE_MFMA16 1
#endif
#endif

__device__ inline unsigned pack2bf(float a, float b) {
  __hip_bfloat162 t = __float22bfloat162_rn(float2{a, b});
  union { __hip_bfloat162 h; unsigned u; } cv; cv.h = t;
  return cv.u;
}

__device__ inline bf16x4 u2bf4(uint2 u) {
  union { uint2 u; bf16x4 v; } c; c.u = u; return c.v;
}

// PV matmul piece: D = V^T-frag (A) x P-frag (B) + C at K=16 granularity.
__device__ inline f32x4 pv_mfma(bf16x4 va, bf16x4 vb, f32x4 c) {
#ifdef HAVE_MFMA16
  return __builtin_amdgcn_mfma_f32_16x16x16bf16_1k(va, vb, c, 0, 0, 0);
#else
  const bf16x8 a8 = {va[0], va[1], va[2], va[3], 0, 0, 0, 0};
  const bf16x8 b8 = {vb[0], vb[1], vb[2], vb[3], 0, 0, 0, 0};
  return __builtin_amdgcn_mfma_f32_16x16x32_bf16(a8, b8, c, 0, 0, 0);
#endif
}

__device__ inline void async_cp16(const void* gsrc, void* ldst) {
  __builtin_amdgcn_global_load_lds(
      (const __attribute__((address_space(1))) unsigned int*)gsrc,
      (__attribute__((address_space(3))) unsigned int*)ldst, 16, 0, 0);
}

// ---------------- merged fp32 -> bf16 casts: x, W_qkv, W_out ----------------
__global__ __launch_bounds__(256) void cast3_kernel(
    const float4* __restrict__ x, const float4* __restrict__ wq,
    const float4* __restrict__ wo,
    uint2* __restrict__ xd, uint2* __restrict__ wqd, uint2* __restrict__ wod)
{
  int i = blockIdx.x * 256 + threadIdx.x;   // grid covers exactly 2,097,152
  const float4* s; uint2* d;
  if (i < 1048576) { s = x; d = xd; }
  else if (i < 1048576 + 786432) { i -= 1048576; s = wq; d = wqd; }
  else { i -= 1048576 + 786432; s = wo; d = wod; }
  const float4 f = s[i];
  d[i] = make_uint2(pack2bf(f.x, f.y), pack2bf(f.z, f.w));
}

// ---------------- fp32 -> hi/lo bf16 split cast ----------------
__global__ __launch_bounds__(256) void split_cast_kernel(
    const float4* __restrict__ src, uint2* __restrict__ hi, uint2* __restrict__ lo, int n4)
{
  const int i = blockIdx.x * 256 + threadIdx.x;
  if (i >= n4) return;
  const float4 f = src[i];
  float hf[4], lf[4];
  const float ff[4] = {f.x, f.y, f.z, f.w};
#pragma unroll
  for (int j = 0; j < 4; ++j) {
    const __hip_bfloat16 h = __float2bfloat16(ff[j]);
    hf[j] = __bfloat162float(h);
    lf[j] = ff[j] - hf[j];
  }
  hi[i] = make_uint2(pack2bf(hf[0], hf[1]), pack2bf(hf[2], hf[3]));
  lo[i] = make_uint2(pack2bf(lf[0], lf[1]), pack2bf(lf[2], lf[3]));
}

// ---------------- proj transpose + hi/lo split: [1024 d][512 m] -> [512 m][1024 d] ---
__global__ __launch_bounds__(256) void trans_split_kernel(
    const float* __restrict__ proj, short* __restrict__ th, short* __restrict__ tl)
{
  __shared__ float Ls[64][65];
  const int tid = threadIdx.x;
  const int d0 = blockIdx.x * 64, m0 = blockIdx.y * 64;
  const int r = tid >> 4, c4 = (tid & 15) * 4;
#pragma unroll
  for (int it = 0; it < 4; ++it) {
    const int row = it * 16 + r;
    const float4 v = *(const float4*)&proj[(size_t)(d0 + row) * PH + m0 + c4];
    Ls[row][c4] = v.x; Ls[row][c4+1] = v.y; Ls[row][c4+2] = v.z; Ls[row][c4+3] = v.w;
  }
  __syncthreads();
#pragma unroll
  for (int it = 0; it < 4; ++it) {
    const int row = it * 16 + r;
    float hf[4], lf[4];
#pragma unroll
    for (int j = 0; j < 4; ++j) {
      const float v = Ls[c4 + j][row];
      const __hip_bfloat16 h = __float2bfloat16(v);
      hf[j] = __bfloat162float(h);
      lf[j] = v - hf[j];
    }
    *(uint2*)&th[(size_t)(m0 + row) * Dd + d0 + c4] = make_uint2(pack2bf(hf[0], hf[1]), pack2bf(hf[2], hf[3]));
    *(uint2*)&tl[(size_t)(m0 + row) * Dd + d0 + c4] = make_uint2(pack2bf(lf[0], lf[1]), pack2bf(lf[2], lf[3]));
  }
}

// ---------------- split-bf16 MFMA GEMM for phases: 128n x 64m tile ----------------
// C[n,m] = sum_k p[n,k]*proj[k,m] via hi/lo split (hh + hl + lh). Grid (8, 32).
__global__ __launch_bounds__(256) void gemm_nn_split(
    const short* __restrict__ Ah_g, const short* __restrict__ Al_g,
    const short* __restrict__ Wh_g, const short* __restrict__ Wl_g,
    float* __restrict__ C)
{
  __shared__ __align__(16) short Ah[128 * 32], Al[128 * 32], Wh[64 * 32], Wl[64 * 32];
  const int tid = threadIdx.x;
  const int w = tid >> 6, lane = tid & 63;
  const int l15 = lane & 15, quad = lane >> 4;
  const int n0 = blockIdx.y * 128, m0 = blockIdx.x * 64;

  const int row = tid >> 2, cc = tid & 3;
  const int ksw = (cc ^ (row & 3)) * 8;
  const short* gAh = Ah_g + (size_t)(n0 + row) * Dd + ksw;
  const short* gAl = Al_g + (size_t)(n0 + row) * Dd + ksw;
  const short* gWh = Wh_g + (size_t)(m0 + row) * Dd + ksw;
  const short* gWl = Wl_g + (size_t)(m0 + row) * Dd + ksw;
  short* lAh  = Ah + tid * 8;
  short* lAh2 = Ah + 2048 + tid * 8;
  short* lAl  = Al + tid * 8;
  short* lAl2 = Al + 2048 + tid * 8;
  short* lWh  = Wh + tid * 8;
  short* lWl  = Wl + tid * 8;

  f32x4 acc[2][4];
#pragma unroll
  for (int i = 0; i < 2; ++i)
#pragma unroll
    for (int j = 0; j < 4; ++j) acc[i][j] = f32x4{0.f, 0.f, 0.f, 0.f};

  const int swq = (quad ^ (l15 & 3)) * 8;

  for (int k0 = 0; k0 < Dd; k0 += 32) {
    __syncthreads();
    async_cp16(gAh + k0, lAh);
    async_cp16(gAh + 64 * Dd + k0, lAh2);
    async_cp16(gAl + k0, lAl);
    async_cp16(gAl + 64 * Dd + k0, lAl2);
    async_cp16(gWh + k0, lWh);
    async_cp16(gWl + k0, lWl);
    __syncthreads();

    bf16x8 ah[2], al[2], wh[4], wl[4];
#pragma unroll
    for (int i = 0; i < 2; ++i) {
      ah[i] = *(const bf16x8*)&Ah[(w * 32 + i * 16 + l15) * 32 + swq];
      al[i] = *(const bf16x8*)&Al[(w * 32 + i * 16 + l15) * 32 + swq];
    }
#pragma unroll
    for (int j = 0; j < 4; ++j) {
      wh[j] = *(const bf16x8*)&Wh[(j * 16 + l15) * 32 + swq];
      wl[j] = *(const bf16x8*)&Wl[(j * 16 + l15) * 32 + swq];
    }
#pragma unroll
    for (int i = 0; i < 2; ++i)
#pragma unroll
      for (int j = 0; j < 4; ++j) {
        acc[i][j] = __builtin_amdgcn_mfma_f32_16x16x32_bf16(ah[i], wh[j], acc[i][j], 0, 0, 0);
        acc[i][j] = __builtin_amdgcn_mfma_f32_16x16x32_bf16(ah[i], wl[j], acc[i][j], 0, 0, 0);
        acc[i][j] = __builtin_amdgcn_mfma_f32_16x16x32_bf16(al[i], wh[j], acc[i][j], 0, 0, 0);
      }
  }

#pragma unroll
  for (int i = 0; i < 2; ++i)
#pragma unroll
    for (int r = 0; r < 4; ++r) {
      float* crow = C + (size_t)(n0 + w * 32 + i * 16 + quad * 4 + r) * PH + m0 + l15;
#pragma unroll
      for (int j = 0; j < 4; ++j) crow[j * 16] = acc[i][j][r];
    }
}

// ---------------- qkv GEMM with FUSED rotary/cast/V-transpose epilogue --------------
__global__ __launch_bounds__(256) void gemm_qkv_fused(
    const __hip_bfloat16* __restrict__ A, const __hip_bfloat16* __restrict__ W,
    const float* __restrict__ bias, const float* __restrict__ phases,
    __hip_bfloat16* __restrict__ q_bf, __hip_bfloat16* __restrict__ k_bf,
    __hip_bfloat16* __restrict__ vt_g)
{
  __shared__ __align__(16) short As[128 * 32];
  __shared__ __align__(16) short Ws[128 * 32];
  const int tid = threadIdx.x;
  const int w = tid >> 6, lane = tid & 63;
  const int l15 = lane & 15, quad = lane >> 4;
  const int wn = w >> 1, wm = w & 1;
  const int n0 = blockIdx.y * 128, m0 = blockIdx.x * 128;

  const int row = tid >> 2, cc = tid & 3;
  const int ksw = (cc ^ (row & 3)) * 8;
  const short* gA  = (const short*)A + (size_t)(n0 + row) * Dd + ksw;
  const short* gW  = (const short*)W + (size_t)(m0 + row) * Dd + ksw;
  short* lA  = As + tid * 8;
  short* lA2 = As + 2048 + tid * 8;
  short* lW  = Ws + tid * 8;
  short* lW2 = Ws + 2048 + tid * 8;

  f32x4 acc[4][4];
#pragma unroll
  for (int i = 0; i < 4; ++i)
#pragma unroll
    for (int j = 0; j < 4; ++j) acc[i][j] = f32x4{0.f, 0.f, 0.f, 0.f};

  const int swq = (quad ^ (l15 & 3)) * 8;

  for (int k0 = 0; k0 < Dd; k0 += 32) {
    __syncthreads();
    async_cp16(gA + k0, lA);
    async_cp16(gA + 64 * Dd + k0, lA2);
    async_cp16(gW + k0, lW);
    async_cp16(gW + 64 * Dd + k0, lW2);
    __syncthreads();

    bf16x8 af[4], bf[4];
#pragma unroll
    for (int i = 0; i < 4; ++i)
      af[i] = *(const bf16x8*)&As[(wn * 64 + i * 16 + l15) * 32 + swq];
#pragma unroll
    for (int j = 0; j < 4; ++j)
      bf[j] = *(const bf16x8*)&Ws[(wm * 64 + j * 16 + l15) * 32 + swq];
#pragma unroll
    for (int i = 0; i < 4; ++i)
#pragma unroll
      for (int j = 0; j < 4; ++j)
        acc[i][j] = __builtin_amdgcn_mfma_f32_16x16x32_bf16(af[i], bf[j], acc[i][j], 0, 0, 0);
  }

  float bv[4];
#pragma unroll
  for (int j = 0; j < 4; ++j) bv[j] = bias[m0 + wm * 64 + j * 16 + l15];

  const int region = m0 >> 10;                 // 0=q, 1=k, 2=v (block-uniform)
  const int mloc = (m0 & 1023) + wm * 64;
  const int h = mloc >> 6;

  if (region < 2) {
    __hip_bfloat16* dst = region == 0 ? q_bf : k_bf;
    const float SC = region == 0 ? 0.18033688011112042f : 1.0f;  // (1/8)*log2(e) on q
#pragma unroll
    for (int i = 0; i < 4; ++i)
#pragma unroll
      for (int r = 0; r < 4; ++r) {
        const int n = n0 + wn * 64 + i * 16 + quad * 4 + r;
        const float* phrow = phases + (size_t)n * PH + h * 32;
        __hip_bfloat16* drow = dst + (size_t)n * Dd + h * 64;
#pragma unroll
        for (int pz = 0; pz < 2; ++pz) {
          const float ph = phrow[pz * 16 + l15];
          float sn, cs;
          __sincosf(ph, &sn, &cs);
          const float a1 = acc[i][pz][r] + bv[pz];
          const float a2 = acc[i][pz + 2][r] + bv[pz + 2];
          drow[pz * 16 + l15]      = __float2bfloat16((a1 * cs - a2 * sn) * SC);
          drow[pz * 16 + 32 + l15] = __float2bfloat16((a1 * sn + a2 * cs) * SC);
        }
      }
  } else {
    const int bh = (n0 >> 11) * 16 + h;
    const int tokb = (n0 & 2047) + wn * 64;
#pragma unroll
    for (int i = 0; i < 4; ++i)
#pragma unroll
      for (int j = 0; j < 4; ++j) {
        const uint2 o = make_uint2(
            pack2bf(acc[i][j][0] + bv[j], acc[i][j][1] + bv[j]),
            pack2bf(acc[i][j][2] + bv[j], acc[i][j][3] + bv[j]));
        const int d = j * 16 + l15;
        *(uint2*)&vt_g[(size_t)(bh * 64 + d) * Ll + tokb + i * 16 + quad * 4] = o;
      }
  }
}

// ---------------- bf16 MFMA GEMM (out-proj):  C = bias + A @ W^T, fp32 out ----------
__global__ __launch_bounds__(256) void gemm_bt_bf16(
    const __hip_bfloat16* __restrict__ A, const __hip_bfloat16* __restrict__ W,
    const float* __restrict__ bias, float* __restrict__ C, int K, int M)
{
  __shared__ __align__(16) short As[128 * 32];
  __shared__ __align__(16) short Ws[128 * 32];
  const int tid = threadIdx.x;
  const int w = tid >> 6, lane = tid & 63;
  const int l15 = lane & 15, quad = lane >> 4;
  const int wn = w >> 1, wm = w & 1;
  const int n0 = blockIdx.y * 128, m0 = blockIdx.x * 128;

  const int row = tid >> 2, cc = tid & 3;
  const int ksw = (cc ^ (row & 3)) * 8;
  const short* gA  = (const short*)A + (size_t)(n0 + row) * K + ksw;
  const short* gW  = (const short*)W + (size_t)(m0 + row) * K + ksw;
  short* lA  = As + tid * 8;
  short* lA2 = As + 2048 + tid * 8;
  short* lW  = Ws + tid * 8;
  short* lW2 = Ws + 2048 + tid * 8;

  f32x4 acc[4][4];
#pragma unroll
  for (int i = 0; i < 4; ++i)
#pragma unroll
    for (int j = 0; j < 4; ++j) acc[i][j] = f32x4{0.f, 0.f, 0.f, 0.f};

  const int swq = (quad ^ (l15 & 3)) * 8;

  for (int k0 = 0; k0 < K; k0 += 32) {
    __syncthreads();
    async_cp16(gA + k0, lA);
    async_cp16(gA + 64 * K + k0, lA2);
    async_cp16(gW + k0, lW);
    async_cp16(gW + 64 * K + k0, lW2);
    __syncthreads();

    bf16x8 af[4], bf[4];
#pragma unroll
    for (int i = 0; i < 4; ++i)
      af[i] = *(const bf16x8*)&As[(wn * 64 + i * 16 + l15) * 32 + swq];
#pragma unroll
    for (int j = 0; j < 4; ++j)
      bf[j] = *(const bf16x8*)&Ws[(wm * 64 + j * 16 + l15) * 32 + swq];
#pragma unroll
    for (int i = 0; i < 4; ++i)
#pragma unroll
      for (int j = 0; j < 4; ++j)
        acc[i][j] = __builtin_amdgcn_mfma_f32_16x16x32_bf16(af[i], bf[j], acc[i][j], 0, 0, 0);
  }

  float bv[4];
#pragma unroll
  for (int j = 0; j < 4; ++j) bv[j] = bias[m0 + wm * 64 + j * 16 + l15];
#pragma unroll
  for (int i = 0; i < 4; ++i)
#pragma unroll
    for (int r = 0; r < 4; ++r) {
      float* crow = C + (size_t)(n0 + wn * 64 + i * 16 + quad * 4 + r) * M + m0 + wm * 64 + l15;
#pragma unroll
      for (int j = 0; j < 4; ++j) crow[j * 16] = acc[i][j][r] + bv[j];
    }
}

// ---------------- bf16 MFMA flash attention (reg prefetch + MFMA denominator) -------
// Q-tile 128, K-tile 64. S^T = K·Q^T (exp2 domain, no online max). P packed by
// truncation. PV: O^T = V^T·P at K=16, P frags direct from registers. Denominator
// via ones-row MFMA (lden = 1^T·P): each lane's col l15 = its own q — no VALU
// accumulate, no epilogue shuffles. Next K/V tile prefetched into registers.
__global__ __launch_bounds__(256) void attn_mfma(
    const __hip_bfloat16* __restrict__ q_bf,
    const __hip_bfloat16* __restrict__ k_bf,
    const __hip_bfloat16* __restrict__ vt_g,
    __hip_bfloat16* __restrict__ aout)
{
  __shared__ __align__(16) short Ks[64 * LDK];
  __shared__ __align__(16) short Vt[64 * LDK];

  const int tid = threadIdx.x;
  const int w = tid >> 6;
  const int lane = tid & 63;
  const int l15 = lane & 15;
  const int quad = lane >> 4;

  const int q0 = blockIdx.x * 128;
  const int bh = blockIdx.y;
  const int b = bh >> 4, h = bh & 15;

  bf16x8 qfrag[2][2];
#pragma unroll
  for (int qg = 0; qg < 2; ++qg)
#pragma unroll
    for (int kh = 0; kh < 2; ++kh) {
      const size_t qrow = (size_t)(b * Ll + q0 + w * 32 + qg * 16 + l15);
      qfrag[qg][kh] = *(const bf16x8*)(q_bf + qrow * Dd + h * 64 + kh * 32 + quad * 8);
    }

  f32x4 acc[4][2];
#pragma unroll
  for (int dt = 0; dt < 4; ++dt)
#pragma unroll
    for (int qg = 0; qg < 2; ++qg) acc[dt][qg] = f32x4{0.f, 0.f, 0.f, 0.f};
  f32x4 lden[2] = {f32x4{0.f,0.f,0.f,0.f}, f32x4{0.f,0.f,0.f,0.f}};
  const short one_bf = (short)0x3F80;           // bf16 1.0
  const bf16x4 ones = {one_bf, one_bf, one_bf, one_bf};

  const int srow = tid >> 2, sseg = tid & 3;
  const __hip_bfloat16* kbase = k_bf + (size_t)(b * Ll + srow) * Dd + h * 64 + sseg * 16;
  const __hip_bfloat16* vbase = vt_g + ((size_t)(bh * 64 + srow)) * Ll + sseg * 16;

  // prefetch tile 0 into registers
  uint4 pk0, pk1, pv0, pv1;
  {
    const uint4* kg = (const uint4*)kbase;
    pk0 = kg[0]; pk1 = kg[1];
    const uint4* vg = (const uint4*)vbase;
    pv0 = vg[0]; pv1 = vg[1];
  }

  for (int kt = 0; kt < Ll / 64; ++kt) {
    __syncthreads();   // previous tile's LDS reads complete
    *(uint4*)&Ks[srow * LDK + sseg * 16]     = pk0;
    *(uint4*)&Ks[srow * LDK + sseg * 16 + 8] = pk1;
    *(uint4*)&Vt[srow * LDK + sseg * 16]     = pv0;
    *(uint4*)&Vt[srow * LDK + sseg * 16 + 8] = pv1;
    __syncthreads();

    // issue next tile's global loads (overlap with compute below)
    {
      const int ktn = (kt + 1) & 31;
      const uint4* kg = (const uint4*)(kbase + (size_t)ktn * 64 * Dd);
      pk0 = kg[0]; pk1 = kg[1];
      const uint4* vg = (const uint4*)(vbase + ktn * 64);
      pv0 = vg[0]; pv1 = vg[1];
    }

    f32x4 s[4][2];
#pragma unroll
    for (int n = 0; n < 4; ++n)
#pragma unroll
      for (int qg = 0; qg < 2; ++qg) s[n][qg] = f32x4{0.f, 0.f, 0.f, 0.f};
#pragma unroll
    for (int n = 0; n < 4; ++n)
#pragma unroll
      for (int kh = 0; kh < 2; ++kh) {
        const bf16x8 af = *(const bf16x8*)&Ks[(n * 16 + l15) * LDK + kh * 32 + quad * 8];
        s[n][0] = __builtin_amdgcn_mfma_f32_16x16x32_bf16(af, qfrag[0][kh], s[n][0], 0, 0, 0);
        s[n][1] = __builtin_amdgcn_mfma_f32_16x16x32_bf16(af, qfrag[1][kh], s[n][1], 0, 0, 0);
      }

    // exp2 + truncation-pack (1 v_perm per pair); no VALU denominator
    uint2 bq[4][2];
#pragma unroll
    for (int qg = 0; qg < 2; ++qg)
#pragma unroll
      for (int n = 0; n < 4; ++n) {
        union { float f; unsigned u; } p0, p1, p2, p3;
        p0.f = __builtin_amdgcn_exp2f(s[n][qg][0]);
        p1.f = __builtin_amdgcn_exp2f(s[n][qg][1]);
        p2.f = __builtin_amdgcn_exp2f(s[n][qg][2]);
        p3.f = __builtin_amdgcn_exp2f(s[n][qg][3]);
        bq[n][qg] = make_uint2(__builtin_amdgcn_perm(p1.u, p0.u, 0x07060302u),
                               __builtin_amdgcn_perm(p3.u, p2.u, 0x07060302u));
      }

    // O^T += V^T · P ; denominator += 1^T · P  (all in MFMA pipe)
#pragma unroll
    for (int n = 0; n < 4; ++n) {
      const bf16x4 pb0 = u2bf4(bq[n][0]);
      const bf16x4 pb1 = u2bf4(bq[n][1]);
      lden[0] = pv_mfma(ones, pb0, lden[0]);
      lden[1] = pv_mfma(ones, pb1, lden[1]);
#pragma unroll
      for (int dt = 0; dt < 4; ++dt) {
        const bf16x4 va = *(const bf16x4*)&Vt[(dt * 16 + l15) * LDK + n * 16 + quad * 4];
        acc[dt][0] = pv_mfma(va, pb0, acc[dt][0]);
        acc[dt][1] = pv_mfma(va, pb1, acc[dt][1]);
      }
    }
  }

#pragma unroll
  for (int qg = 0; qg < 2; ++qg) {
    const float linv = 1.f / lden[qg][0];   // all 4 rows identical; col l15 = this q
    const size_t q = (size_t)(b * Ll + q0 + w * 32 + qg * 16 + l15);
#pragma unroll
    for (int dt = 0; dt < 4; ++dt) {
      const uint2 o = make_uint2(
          pack2bf(acc[dt][qg][0] * linv, acc[dt][qg][1] * linv),
          pack2bf(acc[dt][qg][2] * linv, acc[dt][qg][3] * linv));
      *(uint2*)&aout[q * Dd + h * 64 + dt * 16 + quad * 4] = o;
    }
  }
}

extern "C" void kernel_launch(void* const* d_in, const int* in_sizes, int n_in,
                              void* d_out, int out_size, void* d_ws, size_t ws_size,
                              hipStream_t stream) {
  const float* x     = (const float*)d_in[0];
  const float* p     = (const float*)d_in[1];
  const float* W_qkv = (const float*)d_in[2];
  const float* b_qkv = (const float*)d_in[3];
  const float* W_out = (const float*)d_in[4];
  const float* b_out = (const float*)d_in[5];
  const float* proj  = (const float*)d_in[6];
  float* out = (float*)d_out;

  // workspace overlay (58 MiB used, < proven 72 MiB footprint):
  //  [0,8Mi):   phases fp32 (read by fused qkv epilogue)
  //  [8,16Mi):  p_hi  -> (dead after phases gemm) aout_bf
  //  [16,24Mi): p_lo  -> (dead after phases gemm) vt_g
  //  [24,25Mi): projt_hi   [25,26Mi): projt_lo
  //  [26,34Mi): q_bf   [34,42Mi): k_bf
  //  [42,50Mi): x_bf   [50,56Mi): wqkv_bf   [56,58Mi): wout_bf
  char* wsb = (char*)d_ws;
  float*          phases   = (float*)(wsb);
  short*          p_hi     = (short*)(wsb + (8u << 20));
  __hip_bfloat16* aout_bf  = (__hip_bfloat16*)(wsb + (8u << 20));
  short*          p_lo     = (short*)(wsb + (16u << 20));
  __hip_bfloat16* vt_g     = (__hip_bfloat16*)(wsb + (16u << 20));
  short*          projt_hi = (short*)(wsb + (24u << 20));
  short*          projt_lo = (short*)(wsb + (25u << 20));
  __hip_bfloat16* q_bf     = (__hip_bfloat16*)(wsb + (26u << 20));
  __hip_bfloat16* k_bf     = (__hip_bfloat16*)(wsb + (34u << 20));
  __hip_bfloat16* x_bf     = (__hip_bfloat16*)(wsb + (42u << 20));
  __hip_bfloat16* wqkv_bf  = (__hip_bfloat16*)(wsb + (50u << 20));
  __hip_bfloat16* wout_bf  = (__hip_bfloat16*)(wsb + (56u << 20));

  // input prep
  split_cast_kernel<<<4096, 256, 0, stream>>>((const float4*)p, (uint2*)p_hi, (uint2*)p_lo, 1048576);
  trans_split_kernel<<<dim3(Dd / 64, PH / 64), 256, 0, stream>>>(proj, projt_hi, projt_lo);
  cast3_kernel<<<8192, 256, 0, stream>>>((const float4*)x, (const float4*)W_qkv, (const float4*)W_out,
                                         (uint2*)x_bf, (uint2*)wqkv_bf, (uint2*)wout_bf);
  // phases = p @ proj (split-bf16, 128x64 tiles)
  gemm_nn_split<<<dim3(PH / 64, NT / 128), 256, 0, stream>>>(p_hi, p_lo, projt_hi, projt_lo, phases);
  // qkv GEMM + fused rotary/cast/V-transpose epilogue
  gemm_qkv_fused<<<dim3(D3 / 128, NT / 128), 256, 0, stream>>>(x_bf, wqkv_bf, b_qkv, phases,
                                                               q_bf, k_bf, vt_g);
  // flash attention -> aout bf16
  attn_mfma<<<dim3(Ll / 128, Bb * Hh), 256, 0, stream>>>(q_bf, k_bf, vt_g, aout_bf);
  // out = aout @ W_out^T + b_out
  gemm_bt_bf16<<<dim3(Dd / 128, NT / 128), 256, 0, stream>>>(aout_bf, wout_bf, b_out, out, Dd, Dd);
}